// Round 3
// baseline (2928.638 us; speedup 1.0000x reference)
//
#include <hip/hip_runtime.h>
#include <cmath>

#define NN 1024
#define BC 128
#define LS 24
#define NBLK 256

typedef unsigned short u16;
typedef __attribute__((ext_vector_type(4))) float f32x4;
typedef __attribute__((ext_vector_type(8))) short bf16x8;

typedef __attribute__((address_space(1))) const void* as1cv;
typedef __attribute__((address_space(3))) void* as3v;

#define GLD16(gp, lp) __builtin_amdgcn_global_load_lds((as1cv)(gp), (as3v)(lp), 16, 0, 0)

__device__ __forceinline__ float sigf(float x){ return 1.0f/(1.0f+expf(-x)); }

__device__ __forceinline__ u16 f2b(float x){
  union { float f; unsigned u; } v; v.f = x;
  unsigned r = v.u + 0x7FFFu + ((v.u >> 16) & 1u);
  return (u16)(r >> 16);
}
__device__ __forceinline__ float b2f(u16 b){
  union { unsigned u; float f; } v; v.u = ((unsigned)b) << 16;
  return v.f;
}

// ---------------- preprocessing ----------------

__global__ void k_transpose(const float* __restrict__ in, u16* __restrict__ Xb){
  int idx = blockIdx.x*256 + threadIdx.x;           // BC*NN
  const float* p = in + (size_t)idx*LS;
  #pragma unroll
  for (int t = 0; t < LS; ++t)
    Xb[(size_t)t*BC*NN + idx] = f2b(p[t]);
}

__global__ void k_colsum1(const float* __restrict__ adj, float* __restrict__ part){
  int b = blockIdx.x;                // 64 blocks, 16 rows each
  for (int j = threadIdx.x; j < 1024; j += 256){
    float s = 0.f;
    for (int i = 0; i < 16; ++i) s += adj[(size_t)(b*16+i)*1024 + j];
    part[(size_t)b*1024 + j] = s;
  }
}
__global__ void k_colsum2(const float* __restrict__ part, float* __restrict__ tmp){
  int j = blockIdx.x*256 + threadIdx.x;
  float s = 0.f;
  for (int b = 0; b < 64; ++b) s += part[(size_t)b*1024 + j];
  tmp[j] = (s == 0.f) ? 1e-5f : s;
}

__global__ void k_anorm(const float* __restrict__ adj, const float* __restrict__ tmp,
                        float* __restrict__ anorm, float* __restrict__ A1){
  int idx = blockIdx.x*256 + threadIdx.x;           // 1M
  int i = idx >> 10;
  float v = tmp[i]*adj[idx];
  anorm[idx] = v;
  A1[idx] = fminf(v, 1.f);
}

// C = min(A@B, 1), 1024^3 fp32 (adjacency powers)
__global__ __launch_bounds__(256) void k_gemm_nn(const float* __restrict__ A,
                                                 const float* __restrict__ B,
                                                 float* __restrict__ C){
  __shared__ float As[16][64];
  __shared__ float Bs[16][64];
  int i0 = blockIdx.y*64, j0 = blockIdx.x*64;
  int tid = threadIdx.x;
  int tx = tid & 15, ty = tid >> 4;
  float acc[4][4] = {};
  for (int k0 = 0; k0 < 1024; k0 += 16) {
    {
      int m = tid >> 2, kq = tid & 3;
      float4 v = *(const float4*)(A + (size_t)(i0+m)*1024 + k0 + kq*4);
      As[kq*4+0][m]=v.x; As[kq*4+1][m]=v.y; As[kq*4+2][m]=v.z; As[kq*4+3][m]=v.w;
    }
    {
      int k = tid >> 6, j = tid & 63;
      #pragma unroll
      for (int r = 0; r < 4; ++r)
        Bs[k + r*4][j] = B[(size_t)(k0 + k + r*4)*1024 + j0 + j];
    }
    __syncthreads();
    #pragma unroll
    for (int k = 0; k < 16; ++k) {
      float4 a = *(const float4*)&As[k][ty*4];
      float4 b = *(const float4*)&Bs[k][tx*4];
      acc[0][0]+=a.x*b.x; acc[0][1]+=a.x*b.y; acc[0][2]+=a.x*b.z; acc[0][3]+=a.x*b.w;
      acc[1][0]+=a.y*b.x; acc[1][1]+=a.y*b.y; acc[1][2]+=a.y*b.z; acc[1][3]+=a.y*b.w;
      acc[2][0]+=a.z*b.x; acc[2][1]+=a.z*b.y; acc[2][2]+=a.z*b.z; acc[2][3]+=a.z*b.w;
      acc[3][0]+=a.w*b.x; acc[3][1]+=a.w*b.y; acc[3][2]+=a.w*b.z; acc[3][3]+=a.w*b.w;
    }
    __syncthreads();
  }
  #pragma unroll
  for (int r = 0; r < 4; ++r) {
    float4 o4 = make_float4(fminf(acc[r][0],1.f), fminf(acc[r][1],1.f),
                            fminf(acc[r][2],1.f), fminf(acc[r][3],1.f));
    *(float4*)(C + (size_t)(i0+ty*4+r)*1024 + j0 + tx*4) = o4;
  }
}

__global__ void k_nbr(const float* __restrict__ A3, const float* __restrict__ nw,
                      float* __restrict__ nbr){
  __shared__ float red[256];
  int row = blockIdx.x;
  float s = 0.f;
  for (int j = threadIdx.x; j < 1024; j += 256)
    s += A3[(size_t)row*1024 + j]*nw[j];
  red[threadIdx.x] = s; __syncthreads();
  for (int st = 128; st > 0; st >>= 1){
    if (threadIdx.x < st) red[threadIdx.x] += red[threadIdx.x+st];
    __syncthreads();
  }
  if (threadIdx.x == 0) nbr[row] = red[0];
}

__global__ void k_effw(const float* __restrict__ A, const float* __restrict__ gcw,
                       u16* __restrict__ effb){
  int idx = blockIdx.x*256 + threadIdx.x;
  effb[idx] = f2b(A[idx]*gcw[idx]);
}

// Wgxb standard rows (seg*1024+j) x 3072; WgHp permuted rows p=(j>>3)*32+seg*8+(j&7) x 1024
__global__ void k_packW(const float* __restrict__ Wf, const float* __restrict__ Wi,
                        const float* __restrict__ Wo, const float* __restrict__ Wc,
                        u16* __restrict__ Wgxb, u16* __restrict__ WgHp){
  int idx = blockIdx.x*256 + threadIdx.x;           // 4*1024*4096
  int k = idx & 4095; int r = idx >> 12;
  int seg = r >> 10, j = r & 1023;
  const float* W = seg==0?Wf: seg==1?Wi: seg==2?Wo:Wc;
  float v = W[(size_t)j*4096 + k];
  if (k < 3072) Wgxb[(size_t)r*3072 + k] = f2b(v);
  else {
    int p = (j>>3)*32 + seg*8 + (j&7);
    WgHp[(size_t)p*1024 + (k-3072)] = f2b(v);
  }
}
__global__ void k_packrW(const float* __restrict__ rWf, const float* __restrict__ rWi,
                         const float* __restrict__ rWo, const float* __restrict__ rWc,
                         u16* __restrict__ rWgxb, u16* __restrict__ rWgHp){
  int idx = blockIdx.x*256 + threadIdx.x;           // 4*1024*2048
  int k = idx & 2047; int r = idx >> 11;
  int seg = r >> 10, j = r & 1023;
  const float* W = seg==0?rWf: seg==1?rWi: seg==2?rWo:rWc;
  float v = W[(size_t)j*2048 + k];
  if (k < 1024) rWgxb[(size_t)r*1024 + k] = f2b(v);
  else {
    int p = (j>>3)*32 + seg*8 + (j&7);
    rWgHp[(size_t)p*1024 + (k-1024)] = f2b(v);
  }
}
__global__ void k_packbias(const float* __restrict__ bf_, const float* __restrict__ bi_,
                           const float* __restrict__ bo_, const float* __restrict__ bc_,
                           const float* __restrict__ rbf, const float* __restrict__ rbi,
                           const float* __restrict__ rbo, const float* __restrict__ rbc,
                           float* __restrict__ bg, float* __restrict__ rbg){
  int idx = blockIdx.x*256 + threadIdx.x;           // 4096
  int seg = idx >> 10, j = idx & 1023;
  bg[idx]  = (seg==0?bf_: seg==1?bi_: seg==2?bo_:bc_)[j];
  rbg[idx] = (seg==0?rbf: seg==1?rbi: seg==2?rbo:rbc)[j];
}

// ---------------- bf16 MFMA NT GEMM (big precompute GEMMs) ----------------
__device__ __forceinline__ void mfma_tile(
    const u16* __restrict__ A, const u16* __restrict__ Bw, int K,
    const float* __restrict__ bias, const float* __restrict__ add, int ldadd,
    float* __restrict__ outf, u16* __restrict__ outb, int ldc)
{
  __shared__ u16 ldsA[128*64];
  __shared__ u16 ldsB[128*64];
  const int tid  = threadIdx.x;
  const int lane = tid & 63;
  const int w    = tid >> 6;
  const int wr   = (w >> 1) * 64;
  const int wc   = (w & 1) * 64;
  f32x4 acc[4][4] = {};

  const int lrow = lane >> 3;
  const int srck = ((lane & 7) ^ lrow) * 8;

  for (int k0 = 0; k0 < K; k0 += 64) {
    #pragma unroll
    for (int c = 0; c < 4; ++c) {
      int row = w*32 + c*8;
      GLD16(A  + (size_t)(row + lrow)*K + k0 + srck, &ldsA[row*64]);
      GLD16(Bw + (size_t)(row + lrow)*K + k0 + srck, &ldsB[row*64]);
    }
    __syncthreads();
    #pragma unroll
    for (int kk = 0; kk < 2; ++kk) {
      bf16x8 af[4], bfr[4];
      #pragma unroll
      for (int mi = 0; mi < 4; ++mi) {
        int row = wr + mi*16 + (lane & 15);
        int grp = (kk*4 + (lane >> 4)) ^ (row & 7);
        af[mi] = *(const bf16x8*)&ldsA[row*64 + grp*8];
      }
      #pragma unroll
      for (int ni = 0; ni < 4; ++ni) {
        int row = wc + ni*16 + (lane & 15);
        int grp = (kk*4 + (lane >> 4)) ^ (row & 7);
        bfr[ni] = *(const bf16x8*)&ldsB[row*64 + grp*8];
      }
      #pragma unroll
      for (int mi = 0; mi < 4; ++mi)
        #pragma unroll
        for (int ni = 0; ni < 4; ++ni)
          acc[mi][ni] = __builtin_amdgcn_mfma_f32_16x16x32_bf16(af[mi], bfr[ni], acc[mi][ni], 0, 0, 0);
    }
    __syncthreads();
  }
  #pragma unroll
  for (int mi = 0; mi < 4; ++mi) {
    #pragma unroll
    for (int ni = 0; ni < 4; ++ni) {
      int col = wc + ni*16 + (lane & 15);
      #pragma unroll
      for (int q = 0; q < 4; ++q) {
        int row = wr + mi*16 + (lane >> 4)*4 + q;
        float v = acc[mi][ni][q];
        if (bias) v += bias[col];
        if (add)  v += add[(size_t)row*ldadd + col];
        if (outf) outf[(size_t)row*ldc + col] = v;
        if (outb) outb[(size_t)row*ldc + col] = f2b(v);
      }
    }
  }
}

__global__ __launch_bounds__(256) void k_mfma_nt(
    const u16* __restrict__ A, const u16* __restrict__ B, int K,
    const float* __restrict__ bias, float* __restrict__ outf,
    u16* __restrict__ outb, int ldc)
{
  size_t i0 = (size_t)blockIdx.y * 128, j0 = (size_t)blockIdx.x * 128;
  mfma_tile(A + i0*K, B + j0*K, K,
            bias ? bias + j0 : nullptr, nullptr, 0,
            outf ? outf + i0*ldc + j0 : nullptr,
            outb ? outb + i0*ldc + j0 : nullptr, ldc);
}

// ---------------- persistent recurrence kernel ----------------
// 256 blocks x 512 threads. block = (job, s): job 0 = g/H-LSTM, job 1 = r-LSTM.
// Tile: all 128 batch rows x 32 packed cols (4 segs x 8 gate cols), K=1024.
// Cs/rCs live in registers; H/rH double-buffered bf16 in global; grid barrier per step.
__global__ __launch_bounds__(512) void k_loop(
    const u16* __restrict__ WgHp, const u16* __restrict__ rWgHp,
    const float* __restrict__ gpre, const float* __restrict__ rpre,
    const float* __restrict__ nbrv,
    u16* __restrict__ Hb2, u16* __restrict__ rHb2,
    float* __restrict__ Hf, float* __restrict__ rHf,
    int* __restrict__ bar)
{
  __shared__ u16 ldsA[128*64];     // 16 KB; aliased as O (128x32 f32) after K-loop
  __shared__ u16 ldsB[32*64];      // 4 KB
  float* O = (float*)ldsA;

  const int tid  = threadIdx.x;
  const int lane = tid & 63;
  const int w    = tid >> 6;            // 0..7
  const int wr   = (w >> 1)*32;         // row group
  const int wc   = (w & 1)*16;          // pcol group
  const int bid  = blockIdx.x;
  const int job  = bid >> 7;            // 0..1
  const int s    = bid & 127;           // col slice (8 gate cols)

  const u16* Bp = (job ? rWgHp : WgHp) + (size_t)s*32*1024;
  const float* pre0 = job ? rpre : gpre;
  u16* Hbuf = job ? rHb2 : Hb2;
  float* Hffin = job ? rHf : Hf;

  const int crow = tid >> 2;            // gate cell row 0..127
  const int cn0  = (tid & 3)*2;         // ncol base
  float csr[2] = {0.f, 0.f};
  float fac[2];
  #pragma unroll
  for (int q = 0; q < 2; ++q)
    fac[q] = job ? 1.f : nbrv[s*8 + cn0 + q];

  const int lrow  = lane >> 3;
  const int srcko = ((lane & 7) ^ lrow)*8;

  for (int t = 0; t < LS; ++t){
    const int ph = t & 1;
    const u16* Ab = Hbuf + ph*(BC*NN);
    const float* pret = pre0 + (size_t)t*BC*4096;
    f32x4 acc[2] = {};

    for (int k0 = 0; k0 < 1024; k0 += 64){
      #pragma unroll
      for (int c = 0; c < 2; ++c){
        int rowb = w*16 + c*8;
        GLD16(Ab + (size_t)(rowb + lrow)*1024 + k0 + srcko, &ldsA[rowb*64]);
      }
      if (w < 4){
        int rowb = w*8;
        GLD16(Bp + (size_t)(rowb + lrow)*1024 + k0 + srcko, &ldsB[rowb*64]);
      }
      __syncthreads();
      #pragma unroll
      for (int kk = 0; kk < 2; ++kk){
        bf16x8 bfv;
        {
          int rowv = wc + (lane & 15);
          int grp = (kk*4 + (lane >> 4)) ^ (rowv & 7);
          bfv = *(const bf16x8*)&ldsB[rowv*64 + grp*8];
        }
        #pragma unroll
        for (int mi = 0; mi < 2; ++mi){
          int rowv = wr + mi*16 + (lane & 15);
          int grp = (kk*4 + (lane >> 4)) ^ (rowv & 7);
          bf16x8 af = *(const bf16x8*)&ldsA[rowv*64 + grp*8];
          acc[mi] = __builtin_amdgcn_mfma_f32_16x16x32_bf16(af, bfv, acc[mi], 0, 0, 0);
        }
      }
      __syncthreads();
    }

    // O = acc + pre  (O aliases ldsA; all reads of ldsA are done)
    {
      int pcol = wc + (lane & 15);
      int gcol = (pcol >> 3)*1024 + s*8 + (pcol & 7);
      #pragma unroll
      for (int mi = 0; mi < 2; ++mi){
        #pragma unroll
        for (int q = 0; q < 4; ++q){
          int row = wr + mi*16 + (lane >> 4)*4 + q;
          O[row*32 + pcol] = acc[mi][q] + pret[(size_t)row*4096 + gcol];
        }
      }
    }
    __syncthreads();

    // gates: 2 cells per thread; Cs in regs
    #pragma unroll
    for (int q = 0; q < 2; ++q){
      int ncol = cn0 + q;
      float v0 = O[crow*32 + 0*8 + ncol];
      float v1 = O[crow*32 + 1*8 + ncol];
      float v2 = O[crow*32 + 2*8 + ncol];
      float v3 = O[crow*32 + 3*8 + ncol];
      float fg = sigf(v0), ig = sigf(v1), og = sigf(v2), ct = tanhf(v3);
      float cs = fg*csr[q]*fac[q] + ig*ct;
      csr[q] = cs;
      float h = og*tanhf(cs);
      int gidx = crow*1024 + s*8 + ncol;
      Hbuf[(ph^1)*(BC*NN) + gidx] = f2b(h);
      if (t == LS-1) Hffin[gidx] = h;
    }

    // grid barrier (slot per step; release/acquire agent fences for XCD L2)
    __threadfence();
    __syncthreads();
    if (tid == 0){
      atomicAdd(&bar[t], 1);
      while (__hip_atomic_load(&bar[t], __ATOMIC_RELAXED, __HIP_MEMORY_SCOPE_AGENT) < NBLK) {}
    }
    __syncthreads();
    __threadfence();
  }
}

// ---------------- last-step statistics (two-stage) ----------------
__global__ void k_var1(const u16* __restrict__ Xl, const u16* __restrict__ gcl,
                       float* __restrict__ part){
  int ch = blockIdx.x & 1, seg = blockIdx.x >> 1;   // 64 blocks
  int tid = threadIdx.x;
  float s1=0.f,q1=0.f,s2=0.f,q2=0.f;
  for (int bb = 0; bb < 2; ++bb){
    int row = (seg*2+bb)*2 + ch;
    const u16* xr = Xl + (size_t)row*1024;
    for (int n = tid; n < 1024; n += 256){ float v = b2f(xr[n]); s1 += v; q1 += v*v; }
    const u16* gr = gcl + (size_t)row*3072;
    for (int n = tid; n < 3072; n += 256){ float v = b2f(gr[n]); s2 += v; q2 += v*v; }
  }
  __shared__ float red[256][4];
  red[tid][0]=s1; red[tid][1]=q1; red[tid][2]=s2; red[tid][3]=q2;
  __syncthreads();
  for (int st = 128; st > 0; st >>= 1){
    if (tid < st){ for (int z = 0; z < 4; ++z) red[tid][z] += red[tid+st][z]; }
    __syncthreads();
  }
  if (tid == 0){ for (int z = 0; z < 4; ++z) part[(size_t)blockIdx.x*4 + z] = red[0][z]; }
}
__global__ void k_var2(const float* __restrict__ part, float* __restrict__ vars){
  int tid = threadIdx.x;
  if (tid < 2){
    float s1=0.f,q1=0.f,s2=0.f,q2=0.f;
    for (int seg = 0; seg < 32; ++seg){
      const float* p = part + (size_t)(seg*2+tid)*4;
      s1 += p[0]; q1 += p[1]; s2 += p[2]; q2 += p[3];
    }
    float n1 = 65536.f, n2 = 196608.f;
    vars[tid]   = (q1 - s1*s1/n1) / (n1 - 1.f);
    vars[2+tid] = (q2 - s2*s2/n2) / (n2 - 1.f);
  }
}

__global__ void k_pred(const float* __restrict__ H, const float* __restrict__ rH,
                       const float* __restrict__ vars, const float* __restrict__ cptr,
                       float* __restrict__ pred){
  int idx = blockIdx.x*256 + threadIdx.x;
  int ch = (idx >> 10) & 1;
  float c0 = cptr[0];
  float v1 = vars[ch], v2 = vars[2+ch];
  pred[idx] = (H[idx]*v1*c0 + rH[idx]*v2) / (v1 + v2*c0);
}

__global__ void k_conv(const float* __restrict__ pred, const float* __restrict__ cw,
                       const float* __restrict__ cb, float* __restrict__ out){
  int idx = blockIdx.x*256 + threadIdx.x;      // 64*24*1024
  int n = idx & 1023;
  int on = idx >> 10;
  int o = on % 24, b = on / 24;
  float p0 = pred[(size_t)(b*2+0)*1024 + n];
  float p1 = pred[(size_t)(b*2+1)*1024 + n];
  out[idx] = p0*cw[o*2+0] + p1*cw[o*2+1] + cb[o];
}

// ---------------- launch ----------------
extern "C" void kernel_launch(void* const* d_in, const int* in_sizes, int n_in,
                              void* d_out, int out_size, void* d_ws, size_t ws_size,
                              hipStream_t stream) {
  const float* inputs = (const float*)d_in[0];
  const float* adj    = (const float*)d_in[1];
  const float* gcw    = (const float*)d_in[2];
  const float* Wf  = (const float*)d_in[3];  const float* bf_ = (const float*)d_in[4];
  const float* Wi  = (const float*)d_in[5];  const float* bi_ = (const float*)d_in[6];
  const float* Wo  = (const float*)d_in[7];  const float* bo_ = (const float*)d_in[8];
  const float* Wc  = (const float*)d_in[9];  const float* bc_ = (const float*)d_in[10];
  const float* rWf = (const float*)d_in[11]; const float* rbf = (const float*)d_in[12];
  const float* rWi = (const float*)d_in[13]; const float* rbi = (const float*)d_in[14];
  const float* rWo = (const float*)d_in[15]; const float* rbo = (const float*)d_in[16];
  const float* rWc = (const float*)d_in[17]; const float* rbc = (const float*)d_in[18];
  const float* nw     = (const float*)d_in[19];
  const float* cscal  = (const float*)d_in[20];
  const float* convw  = (const float*)d_in[21];
  const float* convb  = (const float*)d_in[22];
  float* out = (float*)d_out;

  char* cur = (char*)d_ws;
  auto alloc = [&](size_t bytes) -> void* {
    void* p = cur; cur += (bytes + 255) & ~(size_t)255; return p;
  };
  u16*   Xb    = (u16*)  alloc((size_t)LS*BC*NN*2);
  float* csum  = (float*)alloc((size_t)64*1024*4);
  float* tmpv  = (float*)alloc(1024*4);
  float* anorm = (float*)alloc((size_t)NN*NN*4);
  float* Abuf  = (float*)alloc((size_t)3*NN*NN*4);        // A1,A2,A3
  float* nbrv  = (float*)alloc(1024*4);
  u16*   effb  = (u16*)  alloc((size_t)3*NN*NN*2);
  u16*   Wgxb  = (u16*)  alloc((size_t)4096*3072*2);
  u16*   WgHp  = (u16*)  alloc((size_t)4096*1024*2);
  u16*   rWgxb = (u16*)  alloc((size_t)4096*1024*2);
  u16*   rWgHp = (u16*)  alloc((size_t)4096*1024*2);
  float* bgp   = (float*)alloc(4096*4);
  float* rbgp  = (float*)alloc(4096*4);
  u16*   gcb   = (u16*)  alloc((size_t)3072*3072*2);
  float* gpre  = (float*)alloc((size_t)3072*4096*4);
  float* rpre  = (float*)alloc((size_t)3072*4096*4);
  // zero-init region: Hb2, rHb2, bar (contiguous)
  char*  zbase = cur;
  u16*   Hb2   = (u16*)  alloc((size_t)2*BC*NN*2);
  u16*   rHb2  = (u16*)  alloc((size_t)2*BC*NN*2);
  int*   bar   = (int*)  alloc(LS*4);
  size_t zlen  = (size_t)(cur - zbase);
  float* Hfv   = (float*)alloc((size_t)BC*NN*4);
  float* rHfv  = (float*)alloc((size_t)BC*NN*4);
  float* pred  = (float*)alloc((size_t)BC*NN*4);
  float* vars  = (float*)alloc(16*4);
  float* part  = (float*)alloc(64*4*4);

  float* A1 = Abuf;
  float* A2 = Abuf + (size_t)NN*NN;
  float* A3 = Abuf + (size_t)2*NN*NN;

  // preprocessing
  k_transpose<<<(BC*NN)/256, 256, 0, stream>>>(inputs, Xb);
  k_colsum1<<<64, 256, 0, stream>>>(adj, csum);
  k_colsum2<<<4, 256, 0, stream>>>(csum, tmpv);
  k_anorm<<<(NN*NN)/256, 256, 0, stream>>>(adj, tmpv, anorm, A1);
  dim3 gsq(16, 16);
  k_gemm_nn<<<gsq, 256, 0, stream>>>(A1, anorm, A2);
  k_gemm_nn<<<gsq, 256, 0, stream>>>(A2, anorm, A3);
  k_nbr<<<NN, 256, 0, stream>>>(A3, nw, nbrv);
  k_effw<<<(3*NN*NN)/256, 256, 0, stream>>>(Abuf, gcw, effb);
  k_packW<<<(4*1024*4096)/256, 256, 0, stream>>>(Wf, Wi, Wo, Wc, Wgxb, WgHp);
  k_packrW<<<(4*1024*2048)/256, 256, 0, stream>>>(rWf, rWi, rWo, rWc, rWgxb, rWgHp);
  k_packbias<<<16, 256, 0, stream>>>(bf_, bi_, bo_, bc_, rbf, rbi, rbo, rbc, bgp, rbgp);

  // big GEMMs (bf16 MFMA)
  dim3 ggc(24, 24);   // gc_all: 3072x3072, K=1024 -> bf16 out
  k_mfma_nt<<<ggc, 256, 0, stream>>>(Xb, effb, 1024, nullptr, nullptr, gcb, 3072);
  dim3 gpr(32, 24);   // rpre: 3072x4096, K=1024
  k_mfma_nt<<<gpr, 256, 0, stream>>>(Xb, rWgxb, 1024, rbgp, rpre, nullptr, 4096);
  // gpre: 3072x4096, K=3072
  k_mfma_nt<<<gpr, 256, 0, stream>>>(gcb, Wgxb, 3072, bgp, gpre, nullptr, 4096);

  // zero H buffers + barrier slots
  hipMemsetAsync(zbase, 0, zlen, stream);

  // persistent 24-step recurrence
  k_loop<<<NBLK, 512, 0, stream>>>(WgHp, rWgHp, gpre, rpre, nbrv,
                                   Hb2, rHb2, Hfv, rHfv, bar);

  k_var1<<<64, 256, 0, stream>>>(Xb + (size_t)(LS-1)*BC*NN, gcb + (size_t)(LS-1)*BC*3072, part);
  k_var2<<<1, 64, 0, stream>>>(part, vars);
  k_pred<<<(BC*NN)/256, 256, 0, stream>>>(Hfv, rHfv, vars, cscal, pred);
  k_conv<<<(64*24*1024)/256, 256, 0, stream>>>(pred, convw, convb, out);
}

// Round 4
// 759.173 us; speedup vs baseline: 3.8577x; 3.8577x over previous
//
#include <hip/hip_runtime.h>
#include <cmath>

#define NN 1024
#define BC 128
#define LS 24

typedef unsigned short u16;
typedef __attribute__((ext_vector_type(4))) float f32x4;
typedef __attribute__((ext_vector_type(8))) short bf16x8;

typedef __attribute__((address_space(1))) const void* as1cv;
typedef __attribute__((address_space(3))) void* as3v;

#define GLD16(gp, lp) __builtin_amdgcn_global_load_lds((as1cv)(gp), (as3v)(lp), 16, 0, 0)

__device__ __forceinline__ float sigf(float x){ return 1.0f/(1.0f+expf(-x)); }

__device__ __forceinline__ u16 f2b(float x){
  union { float f; unsigned u; } v; v.f = x;
  unsigned r = v.u + 0x7FFFu + ((v.u >> 16) & 1u);
  return (u16)(r >> 16);
}
__device__ __forceinline__ float b2f(u16 b){
  union { unsigned u; float f; } v; v.u = ((unsigned)b) << 16;
  return v.f;
}

// ---------------- preprocessing ----------------

__global__ void k_transpose(const float* __restrict__ in, u16* __restrict__ Xb){
  int idx = blockIdx.x*256 + threadIdx.x;           // BC*NN
  const float4* p = (const float4*)(in + (size_t)idx*LS);   // 96B stride -> 16B aligned
  float v[LS];
  #pragma unroll
  for (int q = 0; q < 6; ++q){
    float4 f = p[q];
    v[q*4]=f.x; v[q*4+1]=f.y; v[q*4+2]=f.z; v[q*4+3]=f.w;
  }
  #pragma unroll
  for (int t = 0; t < LS; ++t)
    Xb[(size_t)t*BC*NN + idx] = f2b(v[t]);
}

__global__ void k_colsum1(const float* __restrict__ adj, float* __restrict__ part){
  int b = blockIdx.x;                // 64 blocks, 16 rows each
  for (int j = threadIdx.x; j < 1024; j += 256){
    float s = 0.f;
    for (int i = 0; i < 16; ++i) s += adj[(size_t)(b*16+i)*1024 + j];
    part[(size_t)b*1024 + j] = s;
  }
}
__global__ void k_colsum2(const float* __restrict__ part, float* __restrict__ tmp){
  int j = blockIdx.x*256 + threadIdx.x;
  float s = 0.f;
  for (int b = 0; b < 64; ++b) s += part[(size_t)b*1024 + j];
  tmp[j] = (s == 0.f) ? 1e-5f : s;
}

// anorm f32 + A1b = bf16(min(anorm,1))
__global__ void k_anorm(const float* __restrict__ adj, const float* __restrict__ tmp,
                        float* __restrict__ anorm, u16* __restrict__ A1b){
  int idx = blockIdx.x*256 + threadIdx.x;           // 1M
  int i = idx >> 10;
  float v = tmp[i]*adj[idx];
  anorm[idx] = v;
  A1b[idx] = f2b(fminf(v, 1.f));
}

// anormTb = bf16(anorm^T), tiled
__global__ void k_transA(const float* __restrict__ in, u16* __restrict__ out){
  __shared__ u16 t[64][65];
  int bi = blockIdx.y*64, bj = blockIdx.x*64;
  for (int e = threadIdx.x; e < 4096; e += 256){
    int r = e >> 6, cc = e & 63;
    t[r][cc] = f2b(in[(size_t)(bi+r)*1024 + bj+cc]);
  }
  __syncthreads();
  for (int e = threadIdx.x; e < 4096; e += 256){
    int r = e >> 6, cc = e & 63;
    out[(size_t)(bj+r)*1024 + bi+cc] = t[cc][r];
  }
}

// nbr[row] = sum_j A3b[row,j]*nw[j]
__global__ void k_nbr(const u16* __restrict__ A3b, const float* __restrict__ nw,
                      float* __restrict__ nbr){
  __shared__ float red[256];
  int row = blockIdx.x;
  float s = 0.f;
  for (int j = threadIdx.x; j < 1024; j += 256)
    s += b2f(A3b[(size_t)row*1024 + j])*nw[j];
  red[threadIdx.x] = s; __syncthreads();
  for (int st = 128; st > 0; st >>= 1){
    if (threadIdx.x < st) red[threadIdx.x] += red[threadIdx.x+st];
    __syncthreads();
  }
  if (threadIdx.x == 0) nbr[row] = red[0];
}

// effb = bf16(Apow * gcw), plus transposed effbT (1024 x 3072)
__global__ void k_effT(const u16* __restrict__ Ap, const float* __restrict__ gcw,
                       u16* __restrict__ effb, u16* __restrict__ effbT){
  __shared__ u16 t[64][65];
  int bi = blockIdx.y*64, bj = blockIdx.x*64;   // bi over 3072, bj over 1024
  for (int e = threadIdx.x; e < 4096; e += 256){
    int r = e >> 6, cc = e & 63;
    size_t idx = (size_t)(bi+r)*1024 + bj+cc;
    u16 v = f2b(b2f(Ap[idx]) * gcw[idx]);
    effb[idx] = v;
    t[r][cc] = v;
  }
  __syncthreads();
  for (int e = threadIdx.x; e < 4096; e += 256){
    int r = e >> 6, cc = e & 63;
    effbT[(size_t)(bj+r)*3072 + bi+cc] = t[cc][r];
  }
}

// Wgxb rows (seg*1024+j) x 3072; WgHp permuted rows p=(j>>3)*32+seg*8+(j&7) x 1024
__global__ void k_packW(const float* __restrict__ Wf, const float* __restrict__ Wi,
                        const float* __restrict__ Wo, const float* __restrict__ Wc,
                        u16* __restrict__ Wgxb, u16* __restrict__ WgHp){
  int idx = blockIdx.x*256 + threadIdx.x;           // 4*1024*4096
  int k = idx & 4095; int r = idx >> 12;
  int seg = r >> 10, j = r & 1023;
  const float* W = seg==0?Wf: seg==1?Wi: seg==2?Wo:Wc;
  float v = W[(size_t)j*4096 + k];
  if (k < 3072) Wgxb[(size_t)r*3072 + k] = f2b(v);
  else {
    int p = (j>>3)*32 + seg*8 + (j&7);
    WgHp[(size_t)p*1024 + (k-3072)] = f2b(v);
  }
}
__global__ void k_packrW(const float* __restrict__ rWf, const float* __restrict__ rWi,
                         const float* __restrict__ rWo, const float* __restrict__ rWc,
                         u16* __restrict__ rWgxb, u16* __restrict__ rWgHp){
  int idx = blockIdx.x*256 + threadIdx.x;           // 4*1024*2048
  int k = idx & 2047; int r = idx >> 11;
  int seg = r >> 10, j = r & 1023;
  const float* W = seg==0?rWf: seg==1?rWi: seg==2?rWo:rWc;
  float v = W[(size_t)j*2048 + k];
  if (k < 1024) rWgxb[(size_t)r*1024 + k] = f2b(v);
  else {
    int p = (j>>3)*32 + seg*8 + (j&7);
    rWgHp[(size_t)p*1024 + (k-1024)] = f2b(v);
  }
}
__global__ void k_packbias(const float* __restrict__ bf_, const float* __restrict__ bi_,
                           const float* __restrict__ bo_, const float* __restrict__ bc_,
                           const float* __restrict__ rbf, const float* __restrict__ rbi,
                           const float* __restrict__ rbo, const float* __restrict__ rbc,
                           float* __restrict__ bg, float* __restrict__ rbg){
  int idx = blockIdx.x*256 + threadIdx.x;           // 4096
  int seg = idx >> 10, j = idx & 1023;
  bg[idx]  = (seg==0?bf_: seg==1?bi_: seg==2?bo_:bc_)[j];
  rbg[idx] = (seg==0?rbf: seg==1?rbi: seg==2?rbo:rbc)[j];
}

// ---------------- bf16 MFMA NT GEMM (precompute GEMMs) ----------------
// out[i,j] = sum_k A[i,k]*B[j,k] (+bias[j]); optional min(.,1) clamp.
__device__ __forceinline__ void mfma_tile(
    const u16* __restrict__ A, const u16* __restrict__ Bw, int K,
    const float* __restrict__ bias, int clamp1,
    float* __restrict__ outf, u16* __restrict__ outb, int ldc)
{
  __shared__ u16 ldsA[128*64];
  __shared__ u16 ldsB[128*64];
  const int tid  = threadIdx.x;
  const int lane = tid & 63;
  const int w    = tid >> 6;
  const int wr   = (w >> 1) * 64;
  const int wc   = (w & 1) * 64;
  f32x4 acc[4][4] = {};

  const int lrow = lane >> 3;
  const int srck = ((lane & 7) ^ lrow) * 8;

  for (int k0 = 0; k0 < K; k0 += 64) {
    #pragma unroll
    for (int c = 0; c < 4; ++c) {
      int row = w*32 + c*8;
      GLD16(A  + (size_t)(row + lrow)*K + k0 + srck, &ldsA[row*64]);
      GLD16(Bw + (size_t)(row + lrow)*K + k0 + srck, &ldsB[row*64]);
    }
    __syncthreads();
    #pragma unroll
    for (int kk = 0; kk < 2; ++kk) {
      bf16x8 af[4], bfr[4];
      #pragma unroll
      for (int mi = 0; mi < 4; ++mi) {
        int row = wr + mi*16 + (lane & 15);
        int grp = (kk*4 + (lane >> 4)) ^ (row & 7);
        af[mi] = *(const bf16x8*)&ldsA[row*64 + grp*8];
      }
      #pragma unroll
      for (int ni = 0; ni < 4; ++ni) {
        int row = wc + ni*16 + (lane & 15);
        int grp = (kk*4 + (lane >> 4)) ^ (row & 7);
        bfr[ni] = *(const bf16x8*)&ldsB[row*64 + grp*8];
      }
      #pragma unroll
      for (int mi = 0; mi < 4; ++mi)
        #pragma unroll
        for (int ni = 0; ni < 4; ++ni)
          acc[mi][ni] = __builtin_amdgcn_mfma_f32_16x16x32_bf16(af[mi], bfr[ni], acc[mi][ni], 0, 0, 0);
    }
    __syncthreads();
  }
  #pragma unroll
  for (int mi = 0; mi < 4; ++mi) {
    #pragma unroll
    for (int ni = 0; ni < 4; ++ni) {
      int col = wc + ni*16 + (lane & 15);
      #pragma unroll
      for (int q = 0; q < 4; ++q) {
        int row = wr + mi*16 + (lane >> 4)*4 + q;
        float v = acc[mi][ni][q];
        if (bias)   v += bias[col];
        if (clamp1) v = fminf(v, 1.f);
        if (outf) outf[(size_t)row*ldc + col] = v;
        if (outb) outb[(size_t)row*ldc + col] = f2b(v);
      }
    }
  }
}

__global__ __launch_bounds__(256) void k_mfma_nt(
    const u16* __restrict__ A, const u16* __restrict__ B, int K,
    const float* __restrict__ bias, int clamp1, float* __restrict__ outf,
    u16* __restrict__ outb, int ldc)
{
  size_t i0 = (size_t)blockIdx.y * 128, j0 = (size_t)blockIdx.x * 128;
  mfma_tile(A + i0*K, B + j0*K, K,
            bias ? bias + j0 : nullptr, clamp1,
            outf ? outf + i0*ldc + j0 : nullptr,
            outb ? outb + i0*ldc + j0 : nullptr, ldc);
}

// ---------------- fused per-step kernel ----------------
// 512 blocks x 256 thr: job = bid>>8, s = (bid&255)>>1 (8 gate cells), mh = bid&1 (64-row half).
// GEMM M=64,N=32(packed 4segs x 8cells),K=1024 over H_prev; epilogue: +pre, gates, Cs update,
// write H_next bf16 (and final f32). Cs/rCs persistent in global, block-owned.
__global__ __launch_bounds__(256) void k_step(
    const u16* __restrict__ WgHp, const u16* __restrict__ rWgHp,
    const float* __restrict__ gpre_t, const float* __restrict__ rpre_t,
    const float* __restrict__ nbrv,
    u16* __restrict__ Hb2, u16* __restrict__ rHb2,
    float* __restrict__ Cs, float* __restrict__ rCs,
    float* __restrict__ Hf, float* __restrict__ rHf,
    int ph, int last)
{
  __shared__ u16 ldsA[64*64];   // 8 KB
  __shared__ u16 ldsB[32*64];   // 4 KB

  const int tid  = threadIdx.x;
  const int lane = tid & 63;
  const int w    = tid >> 6;          // 0..3
  const int bid  = blockIdx.x;
  const int job  = bid >> 8;
  const int rem  = bid & 255;
  const int s    = rem >> 1;
  const int r0   = (rem & 1) * 64;

  const u16* Bp    = (job ? rWgHp : WgHp) + (size_t)s*32*1024;
  const u16* Ab    = (job ? rHb2 : Hb2) + (size_t)ph*BC*NN + (size_t)r0*NN;
  const float* pret = job ? rpre_t : gpre_t;
  u16* Hnext  = (job ? rHb2 : Hb2) + (size_t)(ph^1)*BC*NN;
  float* Csb  = job ? rCs : Cs;
  float* Hfin = job ? rHf : Hf;

  const int lrow = lane >> 3;
  const int srck = ((lane & 7) ^ lrow)*8;

  f32x4 acc[2] = {};
  for (int k0 = 0; k0 < 1024; k0 += 64){
    #pragma unroll
    for (int c = 0; c < 2; ++c){
      int rowb = w*16 + c*8;
      GLD16(Ab + (size_t)(rowb + lrow)*NN + k0 + srck, &ldsA[rowb*64]);
    }
    { int rowb = w*8;
      GLD16(Bp + (size_t)(rowb + lrow)*1024 + k0 + srck, &ldsB[rowb*64]); }
    __syncthreads();
    #pragma unroll
    for (int kk = 0; kk < 2; ++kk){
      int rowa = w*16 + (lane & 15);
      int grpa = (kk*4 + (lane >> 4)) ^ (rowa & 7);
      bf16x8 af = *(const bf16x8*)&ldsA[rowa*64 + grpa*8];
      #pragma unroll
      for (int ni = 0; ni < 2; ++ni){
        int rowb2 = ni*16 + (lane & 15);
        int grpb = (kk*4 + (lane >> 4)) ^ (rowb2 & 7);
        bf16x8 bv = *(const bf16x8*)&ldsB[rowb2*64 + grpb*8];
        acc[ni] = __builtin_amdgcn_mfma_f32_16x16x32_bf16(af, bv, acc[ni], 0, 0, 0);
      }
    }
    __syncthreads();
  }

  // add pre (per-lane, per-seg) then gather 4 segs via shfl_xor(8)
  #pragma unroll
  for (int ni = 0; ni < 2; ++ni){
    int pcol = ni*16 + (lane & 15);
    int gcol = (pcol >> 3)*1024 + s*8 + (pcol & 7);
    #pragma unroll
    for (int q = 0; q < 4; ++q){
      int row = r0 + w*16 + (lane >> 4)*4 + q;
      acc[ni][q] += pret[(size_t)row*4096 + gcol];
    }
  }
  const bool act = (lane & 15) < 8;
  const int  c   = lane & 7;
  float fac = 1.f;
  if (!job && act) fac = nbrv[s*8 + c];
  #pragma unroll
  for (int q = 0; q < 4; ++q){
    float a0 = acc[0][q], a1 = acc[1][q];
    float p1 = __shfl_xor(a0, 8);   // seg1 (i-gate)
    float p3 = __shfl_xor(a1, 8);   // seg3 (Ct)
    if (act){
      int row = r0 + w*16 + (lane >> 4)*4 + q;
      int col = s*8 + c;
      float fg = sigf(a0), ig = sigf(p1), og = sigf(a1), ct = tanhf(p3);
      size_t cidx = (size_t)row*NN + col;
      float cs = fg*Csb[cidx]*fac + ig*ct;
      Csb[cidx] = cs;
      float h = og*tanhf(cs);
      Hnext[cidx] = f2b(h);
      if (last) Hfin[cidx] = h;
    }
  }
}

// ---------------- last-step statistics (two-stage) ----------------
__global__ void k_var1(const u16* __restrict__ Xl, const u16* __restrict__ gcl,
                       float* __restrict__ part){
  int ch = blockIdx.x & 1, seg = blockIdx.x >> 1;   // 64 blocks
  int tid = threadIdx.x;
  float s1=0.f,q1=0.f,s2=0.f,q2=0.f;
  for (int bb = 0; bb < 2; ++bb){
    int row = (seg*2+bb)*2 + ch;
    const u16* xr = Xl + (size_t)row*1024;
    for (int n = tid; n < 1024; n += 256){ float v = b2f(xr[n]); s1 += v; q1 += v*v; }
    const u16* gr = gcl + (size_t)row*3072;
    for (int n = tid; n < 3072; n += 256){ float v = b2f(gr[n]); s2 += v; q2 += v*v; }
  }
  __shared__ float red[256][4];
  red[tid][0]=s1; red[tid][1]=q1; red[tid][2]=s2; red[tid][3]=q2;
  __syncthreads();
  for (int st = 128; st > 0; st >>= 1){
    if (tid < st){ for (int z = 0; z < 4; ++z) red[tid][z] += red[tid+st][z]; }
    __syncthreads();
  }
  if (tid == 0){ for (int z = 0; z < 4; ++z) part[(size_t)blockIdx.x*4 + z] = red[0][z]; }
}
__global__ void k_var2(const float* __restrict__ part, float* __restrict__ vars){
  int tid = threadIdx.x;
  if (tid < 2){
    float s1=0.f,q1=0.f,s2=0.f,q2=0.f;
    for (int seg = 0; seg < 32; ++seg){
      const float* p = part + (size_t)(seg*2+tid)*4;
      s1 += p[0]; q1 += p[1]; s2 += p[2]; q2 += p[3];
    }
    float n1 = 65536.f, n2 = 196608.f;
    vars[tid]   = (q1 - s1*s1/n1) / (n1 - 1.f);
    vars[2+tid] = (q2 - s2*s2/n2) / (n2 - 1.f);
  }
}

__global__ void k_pred(const float* __restrict__ H, const float* __restrict__ rH,
                       const float* __restrict__ vars, const float* __restrict__ cptr,
                       float* __restrict__ pred){
  int idx = blockIdx.x*256 + threadIdx.x;
  int ch = (idx >> 10) & 1;
  float c0 = cptr[0];
  float v1 = vars[ch], v2 = vars[2+ch];
  pred[idx] = (H[idx]*v1*c0 + rH[idx]*v2) / (v1 + v2*c0);
}

__global__ void k_conv(const float* __restrict__ pred, const float* __restrict__ cw,
                       const float* __restrict__ cb, float* __restrict__ out){
  int idx = blockIdx.x*256 + threadIdx.x;      // 64*24*1024
  int n = idx & 1023;
  int on = idx >> 10;
  int o = on % 24, b = on / 24;
  float p0 = pred[(size_t)(b*2+0)*1024 + n];
  float p1 = pred[(size_t)(b*2+1)*1024 + n];
  out[idx] = p0*cw[o*2+0] + p1*cw[o*2+1] + cb[o];
}

// ---------------- launch ----------------
extern "C" void kernel_launch(void* const* d_in, const int* in_sizes, int n_in,
                              void* d_out, int out_size, void* d_ws, size_t ws_size,
                              hipStream_t stream) {
  const float* inputs = (const float*)d_in[0];
  const float* adj    = (const float*)d_in[1];
  const float* gcw    = (const float*)d_in[2];
  const float* Wf  = (const float*)d_in[3];  const float* bf_ = (const float*)d_in[4];
  const float* Wi  = (const float*)d_in[5];  const float* bi_ = (const float*)d_in[6];
  const float* Wo  = (const float*)d_in[7];  const float* bo_ = (const float*)d_in[8];
  const float* Wc  = (const float*)d_in[9];  const float* bc_ = (const float*)d_in[10];
  const float* rWf = (const float*)d_in[11]; const float* rbf = (const float*)d_in[12];
  const float* rWi = (const float*)d_in[13]; const float* rbi = (const float*)d_in[14];
  const float* rWo = (const float*)d_in[15]; const float* rbo = (const float*)d_in[16];
  const float* rWc = (const float*)d_in[17]; const float* rbc = (const float*)d_in[18];
  const float* nw     = (const float*)d_in[19];
  const float* cscal  = (const float*)d_in[20];
  const float* convw  = (const float*)d_in[21];
  const float* convb  = (const float*)d_in[22];
  float* out = (float*)d_out;

  char* cur = (char*)d_ws;
  auto alloc = [&](size_t bytes) -> void* {
    void* p = cur; cur += (bytes + 255) & ~(size_t)255; return p;
  };
  u16*   Xb     = (u16*)  alloc((size_t)LS*BC*NN*2);      // 6 MB
  float* csum   = (float*)alloc((size_t)64*1024*4);
  float* tmpv   = (float*)alloc(1024*4);
  float* anorm  = (float*)alloc((size_t)NN*NN*4);         // 4 MB
  u16*   anormT = (u16*)  alloc((size_t)NN*NN*2);         // 2 MB
  u16*   Apowb  = (u16*)  alloc((size_t)3*NN*NN*2);       // A1b,A2b,A3b  6 MB
  float* nbrv   = (float*)alloc(1024*4);
  u16*   effb   = (u16*)  alloc((size_t)3*NN*NN*2);       // 6 MB
  u16*   effbT  = (u16*)  alloc((size_t)3*NN*NN*2);       // 6 MB
  u16*   Wgxb   = (u16*)  alloc((size_t)4096*3072*2);     // 24 MB
  u16*   WgHp   = (u16*)  alloc((size_t)4096*1024*2);     // 8 MB
  u16*   rWgxb  = (u16*)  alloc((size_t)4096*1024*2);     // 8 MB
  u16*   rWgHp  = (u16*)  alloc((size_t)4096*1024*2);     // 8 MB
  u16*   Cwb    = (u16*)  alloc((size_t)4096*1024*2);     // 8 MB
  float* bgp    = (float*)alloc(4096*4);
  float* rbgp   = (float*)alloc(4096*4);
  u16*   gclb   = (u16*)  alloc((size_t)BC*3072*2);       // last-step gc
  float* gpre   = (float*)alloc((size_t)3072*4096*4);     // 48 MB
  float* rpre   = (float*)alloc((size_t)3072*4096*4);     // 48 MB
  // zero-init region: Hb2, rHb2, Cs, rCs (contiguous)
  char*  zbase  = cur;
  u16*   Hb2    = (u16*)  alloc((size_t)2*BC*NN*2);
  u16*   rHb2   = (u16*)  alloc((size_t)2*BC*NN*2);
  float* Cs     = (float*)alloc((size_t)BC*NN*4);
  float* rCs    = (float*)alloc((size_t)BC*NN*4);
  size_t zlen   = (size_t)(cur - zbase);
  float* Hfv    = (float*)alloc((size_t)BC*NN*4);
  float* rHfv   = (float*)alloc((size_t)BC*NN*4);
  float* pred   = (float*)alloc((size_t)BC*NN*4);
  float* vars   = (float*)alloc(16*4);
  float* part   = (float*)alloc(64*4*4);

  u16* A1b = Apowb;
  u16* A2b = Apowb + (size_t)NN*NN;
  u16* A3b = Apowb + (size_t)2*NN*NN;

  // preprocessing
  k_transpose<<<(BC*NN)/256, 256, 0, stream>>>(inputs, Xb);
  k_colsum1<<<64, 256, 0, stream>>>(adj, csum);
  k_colsum2<<<4, 256, 0, stream>>>(csum, tmpv);
  k_anorm<<<(NN*NN)/256, 256, 0, stream>>>(adj, tmpv, anorm, A1b);
  dim3 g16(16, 16);
  k_transA<<<g16, 256, 0, stream>>>(anorm, anormT);
  // adjacency powers (bf16 MFMA, clamp): entries are {0,1} U tiny -> bf16-exact
  dim3 g88(8, 8);
  k_mfma_nt<<<g88, 256, 0, stream>>>(A1b, anormT, 1024, nullptr, 1, nullptr, A2b, 1024);
  k_mfma_nt<<<g88, 256, 0, stream>>>(A2b, anormT, 1024, nullptr, 1, nullptr, A3b, 1024);
  k_nbr<<<NN, 256, 0, stream>>>(A3b, nw, nbrv);
  dim3 geff(16, 48);
  k_effT<<<geff, 256, 0, stream>>>(Apowb, gcw, effb, effbT);
  k_packW<<<(4*1024*4096)/256, 256, 0, stream>>>(Wf, Wi, Wo, Wc, Wgxb, WgHp);
  k_packrW<<<(4*1024*2048)/256, 256, 0, stream>>>(rWf, rWi, rWo, rWc, rWgxb, rWgHp);
  k_packbias<<<16, 256, 0, stream>>>(bf_, bi_, bo_, bc_, rbf, rbi, rbo, rbc, bgp, rbgp);

  // Cw = Wgx @ eff  (4096x1024, K=3072): gpre = X @ Cw^T later
  dim3 gcwg(8, 32);
  k_mfma_nt<<<gcwg, 256, 0, stream>>>(Wgxb, effbT, 3072, nullptr, 0, nullptr, Cwb, 1024);
  dim3 gpr(32, 24);
  k_mfma_nt<<<gpr, 256, 0, stream>>>(Xb, Cwb,   1024, bgp,  0, gpre, nullptr, 4096);
  k_mfma_nt<<<gpr, 256, 0, stream>>>(Xb, rWgxb, 1024, rbgp, 0, rpre, nullptr, 4096);
  // last-step gc (for var2 only)
  dim3 ggcl(24, 1);
  k_mfma_nt<<<ggcl, 256, 0, stream>>>(Xb + (size_t)(LS-1)*BC*NN, effb, 1024,
                                      nullptr, 0, nullptr, gclb, 3072);

  hipMemsetAsync(zbase, 0, zlen, stream);

  // 24 fused steps
  for (int t = 0; t < LS; ++t)
    k_step<<<512, 256, 0, stream>>>(WgHp, rWgHp,
        gpre + (size_t)t*BC*4096, rpre + (size_t)t*BC*4096,
        nbrv, Hb2, rHb2, Cs, rCs, Hfv, rHfv, t & 1, t == LS-1);

  k_var1<<<64, 256, 0, stream>>>(Xb + (size_t)(LS-1)*BC*NN, gclb, part);
  k_var2<<<1, 64, 0, stream>>>(part, vars);
  k_pred<<<(BC*NN)/256, 256, 0, stream>>>(Hfv, rHfv, vars, cscal, pred);
  k_conv<<<(64*24*1024)/256, 256, 0, stream>>>(pred, convw, convb, out);
}

// Round 5
// 643.583 us; speedup vs baseline: 4.5505x; 1.1796x over previous
//
#include <hip/hip_runtime.h>
#include <cmath>

#define NN 1024
#define BC 128
#define LS 24

typedef unsigned short u16;
typedef __attribute__((ext_vector_type(4))) float f32x4;
typedef __attribute__((ext_vector_type(8))) short bf16x8;

typedef __attribute__((address_space(1))) const void* as1cv;
typedef __attribute__((address_space(3))) void* as3v;

#define GLD16(gp, lp) __builtin_amdgcn_global_load_lds((as1cv)(gp), (as3v)(lp), 16, 0, 0)

__device__ __forceinline__ float sigf(float x){ return 1.0f/(1.0f+expf(-x)); }

__device__ __forceinline__ u16 f2b(float x){
  union { float f; unsigned u; } v; v.f = x;
  unsigned r = v.u + 0x7FFFu + ((v.u >> 16) & 1u);
  return (u16)(r >> 16);
}
__device__ __forceinline__ float b2f(u16 b){
  union { unsigned u; float f; } v; v.u = ((unsigned)b) << 16;
  return v.f;
}

// ---------------- preprocessing ----------------

__global__ void k_transpose(const float* __restrict__ in, u16* __restrict__ Xb){
  int idx = blockIdx.x*256 + threadIdx.x;           // BC*NN
  const float4* p = (const float4*)(in + (size_t)idx*LS);
  float v[LS];
  #pragma unroll
  for (int q = 0; q < 6; ++q){
    float4 f = p[q];
    v[q*4]=f.x; v[q*4+1]=f.y; v[q*4+2]=f.z; v[q*4+3]=f.w;
  }
  #pragma unroll
  for (int t = 0; t < LS; ++t)
    Xb[(size_t)t*BC*NN + idx] = f2b(v[t]);
}

__global__ void k_colsum1(const float* __restrict__ adj, float* __restrict__ part){
  int b = blockIdx.x;                // 64 blocks, 16 rows each
  for (int j = threadIdx.x; j < 1024; j += 256){
    float s = 0.f;
    for (int i = 0; i < 16; ++i) s += adj[(size_t)(b*16+i)*1024 + j];
    part[(size_t)b*1024 + j] = s;
  }
}
__global__ void k_colsum2(const float* __restrict__ part, float* __restrict__ tmp){
  int j = blockIdx.x*256 + threadIdx.x;
  float s = 0.f;
  for (int b = 0; b < 64; ++b) s += part[(size_t)b*1024 + j];
  tmp[j] = (s == 0.f) ? 1e-5f : s;
}

__global__ void k_anorm(const float* __restrict__ adj, const float* __restrict__ tmp,
                        float* __restrict__ anorm, u16* __restrict__ A1b){
  int idx = blockIdx.x*256 + threadIdx.x;           // 1M
  int i = idx >> 10;
  float v = tmp[i]*adj[idx];
  anorm[idx] = v;
  A1b[idx] = f2b(fminf(v, 1.f));
}

__global__ void k_transA(const float* __restrict__ in, u16* __restrict__ out){
  __shared__ u16 t[64][65];
  int bi = blockIdx.y*64, bj = blockIdx.x*64;
  for (int e = threadIdx.x; e < 4096; e += 256){
    int r = e >> 6, cc = e & 63;
    t[r][cc] = f2b(in[(size_t)(bi+r)*1024 + bj+cc]);
  }
  __syncthreads();
  for (int e = threadIdx.x; e < 4096; e += 256){
    int r = e >> 6, cc = e & 63;
    out[(size_t)(bj+r)*1024 + bi+cc] = t[cc][r];
  }
}

__global__ void k_nbr(const u16* __restrict__ A3b, const float* __restrict__ nw,
                      float* __restrict__ nbr){
  __shared__ float red[256];
  int row = blockIdx.x;
  float s = 0.f;
  for (int j = threadIdx.x; j < 1024; j += 256)
    s += b2f(A3b[(size_t)row*1024 + j])*nw[j];
  red[threadIdx.x] = s; __syncthreads();
  for (int st = 128; st > 0; st >>= 1){
    if (threadIdx.x < st) red[threadIdx.x] += red[threadIdx.x+st];
    __syncthreads();
  }
  if (threadIdx.x == 0) nbr[row] = red[0];
}

__global__ void k_effT(const u16* __restrict__ Ap, const float* __restrict__ gcw,
                       u16* __restrict__ effb, u16* __restrict__ effbT){
  __shared__ u16 t[64][65];
  int bi = blockIdx.y*64, bj = blockIdx.x*64;   // bi over 3072, bj over 1024
  for (int e = threadIdx.x; e < 4096; e += 256){
    int r = e >> 6, cc = e & 63;
    size_t idx = (size_t)(bi+r)*1024 + bj+cc;
    u16 v = f2b(b2f(Ap[idx]) * gcw[idx]);
    effb[idx] = v;
    t[r][cc] = v;
  }
  __syncthreads();
  for (int e = threadIdx.x; e < 4096; e += 256){
    int r = e >> 6, cc = e & 63;
    effbT[(size_t)(bj+r)*3072 + bi+cc] = t[cc][r];
  }
}

__global__ void k_packW(const float* __restrict__ Wf, const float* __restrict__ Wi,
                        const float* __restrict__ Wo, const float* __restrict__ Wc,
                        u16* __restrict__ Wgxb, u16* __restrict__ WgHp){
  int idx = blockIdx.x*256 + threadIdx.x;           // 4*1024*4096
  int k = idx & 4095; int r = idx >> 12;
  int seg = r >> 10, j = r & 1023;
  const float* W = seg==0?Wf: seg==1?Wi: seg==2?Wo:Wc;
  float v = W[(size_t)j*4096 + k];
  if (k < 3072) Wgxb[(size_t)r*3072 + k] = f2b(v);
  else {
    int p = (j>>3)*32 + seg*8 + (j&7);
    WgHp[(size_t)p*1024 + (k-3072)] = f2b(v);
  }
}
__global__ void k_packrW(const float* __restrict__ rWf, const float* __restrict__ rWi,
                         const float* __restrict__ rWo, const float* __restrict__ rWc,
                         u16* __restrict__ rWgxb, u16* __restrict__ rWgHp){
  int idx = blockIdx.x*256 + threadIdx.x;           // 4*1024*2048
  int k = idx & 2047; int r = idx >> 11;
  int seg = r >> 10, j = r & 1023;
  const float* W = seg==0?rWf: seg==1?rWi: seg==2?rWo:rWc;
  float v = W[(size_t)j*2048 + k];
  if (k < 1024) rWgxb[(size_t)r*1024 + k] = f2b(v);
  else {
    int p = (j>>3)*32 + seg*8 + (j&7);
    rWgHp[(size_t)p*1024 + (k-1024)] = f2b(v);
  }
}
__global__ void k_packbias(const float* __restrict__ bf_, const float* __restrict__ bi_,
                           const float* __restrict__ bo_, const float* __restrict__ bc_,
                           const float* __restrict__ rbf, const float* __restrict__ rbi,
                           const float* __restrict__ rbo, const float* __restrict__ rbc,
                           float* __restrict__ bg, float* __restrict__ rbg){
  int idx = blockIdx.x*256 + threadIdx.x;           // 4096
  int seg = idx >> 10, j = idx & 1023;
  bg[idx]  = (seg==0?bf_: seg==1?bi_: seg==2?bo_:bc_)[j];
  rbg[idx] = (seg==0?rbf: seg==1?rbi: seg==2?rbo:rbc)[j];
}

// ---------------- pipelined bf16 MFMA NT 128x128 tile ----------------
__device__ __forceinline__ void stage128(const u16* __restrict__ A, const u16* __restrict__ B,
                                         int K, int k0, u16* lA, u16* lB, int w, int lane){
  const int lrow = lane >> 3;
  const int srck = ((lane & 7) ^ lrow) * 8;
  #pragma unroll
  for (int c = 0; c < 4; ++c){
    int row = w*32 + c*8;
    GLD16(A + (size_t)(row + lrow)*K + k0 + srck, &lA[row*64]);
    GLD16(B + (size_t)(row + lrow)*K + k0 + srck, &lB[row*64]);
  }
}

__device__ __forceinline__ void mfma_tile_pipe(
    const u16* __restrict__ A, const u16* __restrict__ Bw, int K,
    const float* __restrict__ bias, int clamp1,
    float* __restrict__ outf, u16* __restrict__ outb, int ldc)
{
  __shared__ u16 ldsA[2][128*64];
  __shared__ u16 ldsB[2][128*64];
  const int tid  = threadIdx.x;
  const int lane = tid & 63;
  const int w    = tid >> 6;
  const int wr   = (w >> 1) * 64;
  const int wc   = (w & 1) * 64;
  f32x4 acc[4][4] = {};

  const int nt = K >> 6;
  stage128(A, Bw, K, 0, ldsA[0], ldsB[0], w, lane);
  __syncthreads();
  int cur = 0;
  for (int t = 0; t < nt; ++t){
    if (t+1 < nt) stage128(A, Bw, K, (t+1)*64, ldsA[cur^1], ldsB[cur^1], w, lane);
    #pragma unroll
    for (int kk = 0; kk < 2; ++kk) {
      bf16x8 af[4], bfr[4];
      #pragma unroll
      for (int mi = 0; mi < 4; ++mi) {
        int row = wr + mi*16 + (lane & 15);
        int grp = (kk*4 + (lane >> 4)) ^ (row & 7);
        af[mi] = *(const bf16x8*)&ldsA[cur][row*64 + grp*8];
      }
      #pragma unroll
      for (int ni = 0; ni < 4; ++ni) {
        int row = wc + ni*16 + (lane & 15);
        int grp = (kk*4 + (lane >> 4)) ^ (row & 7);
        bfr[ni] = *(const bf16x8*)&ldsB[cur][row*64 + grp*8];
      }
      #pragma unroll
      for (int mi = 0; mi < 4; ++mi)
        #pragma unroll
        for (int ni = 0; ni < 4; ++ni)
          acc[mi][ni] = __builtin_amdgcn_mfma_f32_16x16x32_bf16(af[mi], bfr[ni], acc[mi][ni], 0, 0, 0);
    }
    __syncthreads();
    cur ^= 1;
  }
  #pragma unroll
  for (int mi = 0; mi < 4; ++mi) {
    #pragma unroll
    for (int ni = 0; ni < 4; ++ni) {
      int col = wc + ni*16 + (lane & 15);
      #pragma unroll
      for (int q = 0; q < 4; ++q) {
        int row = wr + mi*16 + (lane >> 4)*4 + q;
        float v = acc[mi][ni][q];
        if (bias)   v += bias[col];
        if (clamp1) v = fminf(v, 1.f);
        if (outf) outf[(size_t)row*ldc + col] = v;
        if (outb) outb[(size_t)row*ldc + col] = f2b(v);
      }
    }
  }
}

__global__ __launch_bounds__(256) void k_mfma_nt(
    const u16* __restrict__ A, const u16* __restrict__ B, int K,
    const float* __restrict__ bias, int clamp1, float* __restrict__ outf,
    u16* __restrict__ outb, int ldc)
{
  size_t i0 = (size_t)blockIdx.y * 128, j0 = (size_t)blockIdx.x * 128;
  mfma_tile_pipe(A + i0*K, B + j0*K, K,
                 bias ? bias + j0 : nullptr, clamp1,
                 outf ? outf + i0*ldc + j0 : nullptr,
                 outb ? outb + i0*ldc + j0 : nullptr, ldc);
}

// Cw GEMM with XCD-aware remap: grid (8,32); XCD q owns M-stripe [q*512, q*512+512).
__global__ __launch_bounds__(256) void k_mfma_cw(
    const u16* __restrict__ A, const u16* __restrict__ B,
    u16* __restrict__ outb)
{
  int id = blockIdx.y*8 + blockIdx.x;   // dispatch xcd = id & 7
  int q = id & 7, l = id >> 3;
  int by = q*4 + (l & 3);               // M panel 0..31 (A stripe per XCD)
  int bx = l >> 2;                      // N panel 0..7
  mfma_tile_pipe(A + (size_t)by*128*3072, B + (size_t)bx*128*3072, 3072,
                 nullptr, 0, nullptr,
                 outb + (size_t)by*128*1024 + bx*128, 1024);
}

// ---------------- fused per-step kernel (pipelined, BK=128) ----------------
// 512 blocks x 256 thr: job = bid>>8, s = (bid&255)>>1 (8 gate cells), mh = bid&1.
// GEMM M=64,N=32,K=1024 over H_prev; epilogue: +pre(bf16), gates, Cs update.
__device__ __forceinline__ void stage_step(const u16* __restrict__ Ab, const u16* __restrict__ Bp,
                                           int k0, u16* lA, u16* lB, int w, int lane){
  const int lrow = lane >> 4;          // 0..3
  const int s4   = lane & 15;
  #pragma unroll
  for (int c = 0; c < 4; ++c){
    int rowb = w*16 + c*4;
    int row = rowb + lrow;
    int srcg = (s4 & 8) | ((s4 & 7) ^ (row & 7));
    GLD16(Ab + (size_t)row*1024 + k0 + srcg*8, &lA[rowb*128]);
  }
  #pragma unroll
  for (int c = 0; c < 2; ++c){
    int rowb = w*8 + c*4;
    int row = rowb + lrow;
    int srcg = (s4 & 8) | ((s4 & 7) ^ (row & 7));
    GLD16(Bp + (size_t)row*1024 + k0 + srcg*8, &lB[rowb*128]);
  }
}

__global__ __launch_bounds__(256) void k_step(
    const u16* __restrict__ WgHp, const u16* __restrict__ rWgHp,
    const u16* __restrict__ pre_t,           // [BC][8192] bf16; job*4096 col offset
    const float* __restrict__ nbrv,
    u16* __restrict__ Hb2, u16* __restrict__ rHb2,
    float* __restrict__ Cs, float* __restrict__ rCs,
    float* __restrict__ Hf, float* __restrict__ rHf,
    int ph, int last)
{
  __shared__ u16 ldsA[2][64*128];   // 32 KB
  __shared__ u16 ldsB[2][32*128];   // 16 KB

  const int tid  = threadIdx.x;
  const int lane = tid & 63;
  const int w    = tid >> 6;          // 0..3
  const int bid  = blockIdx.x;
  const int job  = bid >> 8;
  const int rem  = bid & 255;
  const int s    = rem >> 1;
  const int r0   = (rem & 1) * 64;

  const u16* Bp   = (job ? rWgHp : WgHp) + (size_t)s*32*1024;
  const u16* Ab   = (job ? rHb2 : Hb2) + (size_t)ph*BC*NN + (size_t)r0*NN;
  const u16* pret = pre_t + (size_t)job*4096;
  u16* Hnext  = (job ? rHb2 : Hb2) + (size_t)(ph^1)*BC*NN;
  float* Csb  = job ? rCs : Cs;
  float* Hfin = job ? rHf : Hf;

  f32x4 acc[2] = {};
  stage_step(Ab, Bp, 0, ldsA[0], ldsB[0], w, lane);
  __syncthreads();
  int cur = 0;
  for (int t = 0; t < 8; ++t){
    if (t < 7) stage_step(Ab, Bp, (t+1)*128, ldsA[cur^1], ldsB[cur^1], w, lane);
    #pragma unroll
    for (int kk = 0; kk < 4; ++kk){
      int idx = kk*4 + (lane >> 4);
      int rowa = w*16 + (lane & 15);
      int pa = (idx & 8) | ((idx & 7) ^ (rowa & 7));
      bf16x8 af = *(const bf16x8*)&ldsA[cur][rowa*128 + pa*8];
      #pragma unroll
      for (int ni = 0; ni < 2; ++ni){
        int rowb = ni*16 + (lane & 15);
        int pb = (idx & 8) | ((idx & 7) ^ (rowb & 7));
        bf16x8 bv = *(const bf16x8*)&ldsB[cur][rowb*128 + pb*8];
        acc[ni] = __builtin_amdgcn_mfma_f32_16x16x32_bf16(af, bv, acc[ni], 0, 0, 0);
      }
    }
    __syncthreads();
    cur ^= 1;
  }

  // add pre (bf16), then gather segs via shfl_xor(8)
  #pragma unroll
  for (int ni = 0; ni < 2; ++ni){
    int pcol = ni*16 + (lane & 15);
    int gcol = (pcol >> 3)*1024 + s*8 + (pcol & 7);
    #pragma unroll
    for (int q = 0; q < 4; ++q){
      int row = r0 + w*16 + (lane >> 4)*4 + q;
      acc[ni][q] += b2f(pret[(size_t)row*8192 + gcol]);
    }
  }
  const bool act = (lane & 15) < 8;
  const int  c   = lane & 7;
  float fac = 1.f;
  if (!job && act) fac = nbrv[s*8 + c];
  #pragma unroll
  for (int q = 0; q < 4; ++q){
    float a0 = acc[0][q], a1 = acc[1][q];
    float p1 = __shfl_xor(a0, 8);   // seg1 (i-gate)
    float p3 = __shfl_xor(a1, 8);   // seg3 (Ct)
    if (act){
      int row = r0 + w*16 + (lane >> 4)*4 + q;
      int col = s*8 + c;
      float fg = sigf(a0), ig = sigf(p1), og = sigf(a1), ct = tanhf(p3);
      size_t cidx = (size_t)row*NN + col;
      float cs = fg*Csb[cidx]*fac + ig*ct;
      Csb[cidx] = cs;
      float h = og*tanhf(cs);
      Hnext[cidx] = f2b(h);
      if (last) Hfin[cidx] = h;
    }
  }
}

// ---------------- last-step statistics (two-stage) ----------------
__global__ void k_var1(const u16* __restrict__ Xl, const u16* __restrict__ gcl,
                       float* __restrict__ part){
  int ch = blockIdx.x & 1, seg = blockIdx.x >> 1;   // 64 blocks
  int tid = threadIdx.x;
  float s1=0.f,q1=0.f,s2=0.f,q2=0.f;
  for (int bb = 0; bb < 2; ++bb){
    int row = (seg*2+bb)*2 + ch;
    const u16* xr = Xl + (size_t)row*1024;
    for (int n = tid; n < 1024; n += 256){ float v = b2f(xr[n]); s1 += v; q1 += v*v; }
    const u16* gr = gcl + (size_t)row*3072;
    for (int n = tid; n < 3072; n += 256){ float v = b2f(gr[n]); s2 += v; q2 += v*v; }
  }
  __shared__ float red[256][4];
  red[tid][0]=s1; red[tid][1]=q1; red[tid][2]=s2; red[tid][3]=q2;
  __syncthreads();
  for (int st = 128; st > 0; st >>= 1){
    if (tid < st){ for (int z = 0; z < 4; ++z) red[tid][z] += red[tid+st][z]; }
    __syncthreads();
  }
  if (tid == 0){ for (int z = 0; z < 4; ++z) part[(size_t)blockIdx.x*4 + z] = red[0][z]; }
}
__global__ void k_var2(const float* __restrict__ part, float* __restrict__ vars){
  int tid = threadIdx.x;
  if (tid < 2){
    float s1=0.f,q1=0.f,s2=0.f,q2=0.f;
    for (int seg = 0; seg < 32; ++seg){
      const float* p = part + (size_t)(seg*2+tid)*4;
      s1 += p[0]; q1 += p[1]; s2 += p[2]; q2 += p[3];
    }
    float n1 = 65536.f, n2 = 196608.f;
    vars[tid]   = (q1 - s1*s1/n1) / (n1 - 1.f);
    vars[2+tid] = (q2 - s2*s2/n2) / (n2 - 1.f);
  }
}

__global__ void k_pred(const float* __restrict__ H, const float* __restrict__ rH,
                       const float* __restrict__ vars, const float* __restrict__ cptr,
                       float* __restrict__ pred){
  int idx = blockIdx.x*256 + threadIdx.x;
  int ch = (idx >> 10) & 1;
  float c0 = cptr[0];
  float v1 = vars[ch], v2 = vars[2+ch];
  pred[idx] = (H[idx]*v1*c0 + rH[idx]*v2) / (v1 + v2*c0);
}

__global__ void k_conv(const float* __restrict__ pred, const float* __restrict__ cw,
                       const float* __restrict__ cb, float* __restrict__ out){
  int idx = blockIdx.x*256 + threadIdx.x;      // 64*24*1024
  int n = idx & 1023;
  int on = idx >> 10;
  int o = on % 24, b = on / 24;
  float p0 = pred[(size_t)(b*2+0)*1024 + n];
  float p1 = pred[(size_t)(b*2+1)*1024 + n];
  out[idx] = p0*cw[o*2+0] + p1*cw[o*2+1] + cb[o];
}

// ---------------- launch ----------------
extern "C" void kernel_launch(void* const* d_in, const int* in_sizes, int n_in,
                              void* d_out, int out_size, void* d_ws, size_t ws_size,
                              hipStream_t stream) {
  const float* inputs = (const float*)d_in[0];
  const float* adj    = (const float*)d_in[1];
  const float* gcw    = (const float*)d_in[2];
  const float* Wf  = (const float*)d_in[3];  const float* bf_ = (const float*)d_in[4];
  const float* Wi  = (const float*)d_in[5];  const float* bi_ = (const float*)d_in[6];
  const float* Wo  = (const float*)d_in[7];  const float* bo_ = (const float*)d_in[8];
  const float* Wc  = (const float*)d_in[9];  const float* bc_ = (const float*)d_in[10];
  const float* rWf = (const float*)d_in[11]; const float* rbf = (const float*)d_in[12];
  const float* rWi = (const float*)d_in[13]; const float* rbi = (const float*)d_in[14];
  const float* rWo = (const float*)d_in[15]; const float* rbo = (const float*)d_in[16];
  const float* rWc = (const float*)d_in[17]; const float* rbc = (const float*)d_in[18];
  const float* nw     = (const float*)d_in[19];
  const float* cscal  = (const float*)d_in[20];
  const float* convw  = (const float*)d_in[21];
  const float* convb  = (const float*)d_in[22];
  float* out = (float*)d_out;

  char* cur = (char*)d_ws;
  auto alloc = [&](size_t bytes) -> void* {
    void* p = cur; cur += (bytes + 255) & ~(size_t)255; return p;
  };
  u16*   Xb     = (u16*)  alloc((size_t)LS*BC*NN*2);      // 6 MB
  float* csum   = (float*)alloc((size_t)64*1024*4);
  float* tmpv   = (float*)alloc(1024*4);
  float* anorm  = (float*)alloc((size_t)NN*NN*4);         // 4 MB
  u16*   anormT = (u16*)  alloc((size_t)NN*NN*2);         // 2 MB
  u16*   Apowb  = (u16*)  alloc((size_t)3*NN*NN*2);       // 6 MB
  float* nbrv   = (float*)alloc(1024*4);
  u16*   effb   = (u16*)  alloc((size_t)3*NN*NN*2);       // 6 MB
  u16*   effbT  = (u16*)  alloc((size_t)3*NN*NN*2);       // 6 MB
  u16*   Wgxb   = (u16*)  alloc((size_t)4096*3072*2);     // 24 MB
  u16*   WgHp   = (u16*)  alloc((size_t)4096*1024*2);     // 8 MB
  u16*   rWgHp  = (u16*)  alloc((size_t)4096*1024*2);     // 8 MB
  u16*   Bcat   = (u16*)  alloc((size_t)8192*1024*2);     // 16 MB: [Cw; rWgx]
  float* bgcat  = (float*)alloc(8192*4);
  u16*   gclb   = (u16*)  alloc((size_t)BC*3072*2);
  u16*   prebuf = (u16*)  alloc((size_t)3072*8192*2);     // 48 MB bf16
  char*  zbase  = cur;
  u16*   Hb2    = (u16*)  alloc((size_t)2*BC*NN*2);
  u16*   rHb2   = (u16*)  alloc((size_t)2*BC*NN*2);
  float* Cs     = (float*)alloc((size_t)BC*NN*4);
  float* rCs    = (float*)alloc((size_t)BC*NN*4);
  size_t zlen   = (size_t)(cur - zbase);
  float* Hfv    = (float*)alloc((size_t)BC*NN*4);
  float* rHfv   = (float*)alloc((size_t)BC*NN*4);
  float* pred   = (float*)alloc((size_t)BC*NN*4);
  float* vars   = (float*)alloc(16*4);
  float* part   = (float*)alloc(64*4*4);

  u16* A1b = Apowb;
  u16* A2b = Apowb + (size_t)NN*NN;
  u16* A3b = Apowb + (size_t)2*NN*NN;
  u16* Cwb   = Bcat;                       // rows 0..4095
  u16* rWgxb = Bcat + (size_t)4096*1024;   // rows 4096..8191

  // preprocessing
  k_transpose<<<(BC*NN)/256, 256, 0, stream>>>(inputs, Xb);
  k_colsum1<<<64, 256, 0, stream>>>(adj, csum);
  k_colsum2<<<4, 256, 0, stream>>>(csum, tmpv);
  k_anorm<<<(NN*NN)/256, 256, 0, stream>>>(adj, tmpv, anorm, A1b);
  dim3 g16(16, 16);
  k_transA<<<g16, 256, 0, stream>>>(anorm, anormT);
  dim3 g88(8, 8);
  k_mfma_nt<<<g88, 256, 0, stream>>>(A1b, anormT, 1024, nullptr, 1, nullptr, A2b, 1024);
  k_mfma_nt<<<g88, 256, 0, stream>>>(A2b, anormT, 1024, nullptr, 1, nullptr, A3b, 1024);
  k_nbr<<<NN, 256, 0, stream>>>(A3b, nw, nbrv);
  dim3 geff(16, 48);
  k_effT<<<geff, 256, 0, stream>>>(Apowb, gcw, effb, effbT);
  k_packW<<<(4*1024*4096)/256, 256, 0, stream>>>(Wf, Wi, Wo, Wc, Wgxb, WgHp);
  k_packrW<<<(4*1024*2048)/256, 256, 0, stream>>>(rWf, rWi, rWo, rWc, rWgxb, rWgHp);
  k_packbias<<<16, 256, 0, stream>>>(bf_, bi_, bo_, bc_, rbf, rbi, rbo, rbc,
                                     bgcat, bgcat + 4096);

  // Cw = Wgx @ eff (4096x1024, K=3072), XCD-stripe swizzled
  dim3 gcwg(8, 32);
  k_mfma_cw<<<gcwg, 256, 0, stream>>>(Wgxb, effbT, Cwb);
  // pre = X @ [Cw; rWgx]^T + biascat (3072x8192, K=1024), bf16 out
  dim3 gpre(64, 24);
  k_mfma_nt<<<gpre, 256, 0, stream>>>(Xb, Bcat, 1024, bgcat, 0, nullptr, prebuf, 8192);
  // last-step gc (for var2 only)
  dim3 ggcl(24, 1);
  k_mfma_nt<<<ggcl, 256, 0, stream>>>(Xb + (size_t)(LS-1)*BC*NN, effb, 1024,
                                      nullptr, 0, nullptr, gclb, 3072);

  hipMemsetAsync(zbase, 0, zlen, stream);

  // 24 fused steps
  for (int t = 0; t < LS; ++t)
    k_step<<<512, 256, 0, stream>>>(WgHp, rWgHp,
        prebuf + (size_t)t*BC*8192,
        nbrv, Hb2, rHb2, Cs, rCs, Hfv, rHfv, t & 1, t == LS-1);

  k_var1<<<64, 256, 0, stream>>>(Xb + (size_t)(LS-1)*BC*NN, gclb, part);
  k_var2<<<1, 64, 0, stream>>>(part, vars);
  k_pred<<<(BC*NN)/256, 256, 0, stream>>>(Hfv, rHfv, vars, cscal, pred);
  k_conv<<<(64*24*1024)/256, 256, 0, stream>>>(pred, convw, convb, out);
}

// Round 6
// 618.684 us; speedup vs baseline: 4.7337x; 1.0402x over previous
//
#include <hip/hip_runtime.h>
#include <cmath>

#define NN 1024
#define BC 128
#define LS 24

typedef unsigned short u16;
typedef __attribute__((ext_vector_type(4))) float f32x4;
typedef __attribute__((ext_vector_type(8))) short bf16x8;

typedef __attribute__((address_space(1))) const void* as1cv;
typedef __attribute__((address_space(3))) void* as3v;

#define GLD16(gp, lp) __builtin_amdgcn_global_load_lds((as1cv)(gp), (as3v)(lp), 16, 0, 0)

__device__ __forceinline__ float sigf(float x){ return 1.0f/(1.0f+expf(-x)); }

__device__ __forceinline__ u16 f2b(float x){
  union { float f; unsigned u; } v; v.f = x;
  unsigned r = v.u + 0x7FFFu + ((v.u >> 16) & 1u);
  return (u16)(r >> 16);
}
__device__ __forceinline__ float b2f(u16 b){
  union { unsigned u; float f; } v; v.u = ((unsigned)b) << 16;
  return v.f;
}

// ---------------- preprocessing ----------------

__global__ void k_transpose(const float* __restrict__ in, u16* __restrict__ Xb){
  int idx = blockIdx.x*256 + threadIdx.x;           // BC*NN
  const float4* p = (const float4*)(in + (size_t)idx*LS);
  float v[LS];
  #pragma unroll
  for (int q = 0; q < 6; ++q){
    float4 f = p[q];
    v[q*4]=f.x; v[q*4+1]=f.y; v[q*4+2]=f.z; v[q*4+3]=f.w;
  }
  #pragma unroll
  for (int t = 0; t < LS; ++t)
    Xb[(size_t)t*BC*NN + idx] = f2b(v[t]);
}

__global__ void k_colsum1(const float* __restrict__ adj, float* __restrict__ part){
  int b = blockIdx.x;                // 64 blocks, 16 rows each
  for (int j = threadIdx.x; j < 1024; j += 256){
    float s = 0.f;
    for (int i = 0; i < 16; ++i) s += adj[(size_t)(b*16+i)*1024 + j];
    part[(size_t)b*1024 + j] = s;
  }
}
__global__ void k_colsum2(const float* __restrict__ part, float* __restrict__ tmp){
  int j = blockIdx.x*256 + threadIdx.x;
  float s = 0.f;
  for (int b = 0; b < 64; ++b) s += part[(size_t)b*1024 + j];
  tmp[j] = (s == 0.f) ? 1e-5f : s;
}

// fused: A1b = bf16(min(tmp[i]*adj,1)); anormT = bf16(tmp[i]*adj)^T
__global__ void k_anormT(const float* __restrict__ adj, const float* __restrict__ tmp,
                         u16* __restrict__ A1b, u16* __restrict__ anormT){
  __shared__ u16 t[64][65];
  int bi = blockIdx.y*64, bj = blockIdx.x*64;
  for (int e = threadIdx.x; e < 4096; e += 256){
    int r = e >> 6, cc = e & 63;
    float v = tmp[bi+r]*adj[(size_t)(bi+r)*1024 + bj+cc];
    A1b[(size_t)(bi+r)*1024 + bj+cc] = f2b(fminf(v, 1.f));
    t[r][cc] = f2b(v);
  }
  __syncthreads();
  for (int e = threadIdx.x; e < 4096; e += 256){
    int r = e >> 6, cc = e & 63;
    anormT[(size_t)(bj+r)*1024 + bi+cc] = t[cc][r];
  }
}

__global__ void k_nbr(const u16* __restrict__ A3b, const float* __restrict__ nw,
                      float* __restrict__ nbr){
  __shared__ float red[256];
  int row = blockIdx.x;
  float s = 0.f;
  for (int j = threadIdx.x; j < 1024; j += 256)
    s += b2f(A3b[(size_t)row*1024 + j])*nw[j];
  red[threadIdx.x] = s; __syncthreads();
  for (int st = 128; st > 0; st >>= 1){
    if (threadIdx.x < st) red[threadIdx.x] += red[threadIdx.x+st];
    __syncthreads();
  }
  if (threadIdx.x == 0) nbr[row] = red[0];
}

__global__ void k_effT(const u16* __restrict__ Ap, const float* __restrict__ gcw,
                       u16* __restrict__ effb, u16* __restrict__ effbT){
  __shared__ u16 t[64][65];
  int bi = blockIdx.y*64, bj = blockIdx.x*64;   // bi over 3072, bj over 1024
  for (int e = threadIdx.x; e < 4096; e += 256){
    int r = e >> 6, cc = e & 63;
    size_t idx = (size_t)(bi+r)*1024 + bj+cc;
    u16 v = f2b(b2f(Ap[idx]) * gcw[idx]);
    effb[idx] = v;
    t[r][cc] = v;
  }
  __syncthreads();
  for (int e = threadIdx.x; e < 4096; e += 256){
    int r = e >> 6, cc = e & 63;
    effbT[(size_t)(bj+r)*3072 + bi+cc] = t[cc][r];
  }
}

// merged weight pack; packed-H rows p = (j>>2)*16 + seg*4 + (j&3)
__global__ void k_pack(const float* __restrict__ Wf, const float* __restrict__ Wi,
                       const float* __restrict__ Wo, const float* __restrict__ Wc,
                       const float* __restrict__ rWf, const float* __restrict__ rWi,
                       const float* __restrict__ rWo, const float* __restrict__ rWc,
                       u16* __restrict__ Wgxb, u16* __restrict__ WgHp,
                       u16* __restrict__ rWgxb, u16* __restrict__ rWgHp){
  int idx = blockIdx.x*256 + threadIdx.x;
  if (idx < 16777216){
    int k = idx & 4095, r = idx >> 12, seg = r >> 10, j = r & 1023;
    const float* W = seg==0?Wf: seg==1?Wi: seg==2?Wo:Wc;
    float v = W[(size_t)j*4096 + k];
    if (k < 3072) Wgxb[(size_t)r*3072 + k] = f2b(v);
    else {
      int p = (j>>2)*16 + seg*4 + (j&3);
      WgHp[(size_t)p*1024 + (k-3072)] = f2b(v);
    }
  } else {
    int i2 = idx - 16777216;
    int k = i2 & 2047, r = i2 >> 11, seg = r >> 10, j = r & 1023;
    const float* W = seg==0?rWf: seg==1?rWi: seg==2?rWo:rWc;
    float v = W[(size_t)j*2048 + k];
    if (k < 1024) rWgxb[(size_t)r*1024 + k] = f2b(v);
    else {
      int p = (j>>2)*16 + seg*4 + (j&3);
      rWgHp[(size_t)p*1024 + (k-1024)] = f2b(v);
    }
  }
}
__global__ void k_packbias(const float* __restrict__ bf_, const float* __restrict__ bi_,
                           const float* __restrict__ bo_, const float* __restrict__ bc_,
                           const float* __restrict__ rbf, const float* __restrict__ rbi,
                           const float* __restrict__ rbo, const float* __restrict__ rbc,
                           float* __restrict__ bg, float* __restrict__ rbg){
  int idx = blockIdx.x*256 + threadIdx.x;           // 4096
  int seg = idx >> 10, j = idx & 1023;
  bg[idx]  = (seg==0?bf_: seg==1?bi_: seg==2?bo_:bc_)[j];
  rbg[idx] = (seg==0?rbf: seg==1?rbi: seg==2?rbo:rbc)[j];
}

// ---------------- bf16 MFMA NT GEMM, 128x128 tile, single-buffer (m97 structure) ----------------
__device__ __forceinline__ void stage128(const u16* __restrict__ A, const u16* __restrict__ B,
                                         int K, int k0, u16* lA, u16* lB, int w, int lane){
  const int lrow = lane >> 3;
  const int srck = ((lane & 7) ^ lrow) * 8;
  #pragma unroll
  for (int c = 0; c < 4; ++c){
    int row = w*32 + c*8;
    GLD16(A + (size_t)(row + lrow)*K + k0 + srck, &lA[row*64]);
    GLD16(B + (size_t)(row + lrow)*K + k0 + srck, &lB[row*64]);
  }
}

__device__ __forceinline__ void mfma_tile(
    const u16* __restrict__ A, const u16* __restrict__ Bw, int K,
    const float* __restrict__ bias,
    float* __restrict__ outf, u16* __restrict__ outb, int ldc)
{
  __shared__ u16 ldsA[128*64];
  __shared__ u16 ldsB[128*64];
  const int tid  = threadIdx.x;
  const int lane = tid & 63;
  const int w    = tid >> 6;
  const int wr   = (w >> 1) * 64;
  const int wc   = (w & 1) * 64;
  f32x4 acc[4][4] = {};

  for (int k0 = 0; k0 < K; k0 += 64){
    stage128(A, Bw, K, k0, ldsA, ldsB, w, lane);
    __syncthreads();
    #pragma unroll
    for (int kk = 0; kk < 2; ++kk) {
      bf16x8 af[4], bfr[4];
      #pragma unroll
      for (int mi = 0; mi < 4; ++mi) {
        int row = wr + mi*16 + (lane & 15);
        int grp = (kk*4 + (lane >> 4)) ^ (row & 7);
        af[mi] = *(const bf16x8*)&ldsA[row*64 + grp*8];
      }
      #pragma unroll
      for (int ni = 0; ni < 4; ++ni) {
        int row = wc + ni*16 + (lane & 15);
        int grp = (kk*4 + (lane >> 4)) ^ (row & 7);
        bfr[ni] = *(const bf16x8*)&ldsB[row*64 + grp*8];
      }
      #pragma unroll
      for (int mi = 0; mi < 4; ++mi)
        #pragma unroll
        for (int ni = 0; ni < 4; ++ni)
          acc[mi][ni] = __builtin_amdgcn_mfma_f32_16x16x32_bf16(af[mi], bfr[ni], acc[mi][ni], 0, 0, 0);
    }
    __syncthreads();
  }
  #pragma unroll
  for (int mi = 0; mi < 4; ++mi) {
    #pragma unroll
    for (int ni = 0; ni < 4; ++ni) {
      int col = wc + ni*16 + (lane & 15);
      #pragma unroll
      for (int q = 0; q < 4; ++q) {
        int row = wr + mi*16 + (lane >> 4)*4 + q;
        float v = acc[mi][ni][q];
        if (bias) v += bias[col];
        if (outf) outf[(size_t)row*ldc + col] = v;
        if (outb) outb[(size_t)row*ldc + col] = f2b(v);
      }
    }
  }
}

__global__ __launch_bounds__(256) void k_mfma_nt(
    const u16* __restrict__ A, const u16* __restrict__ B, int K,
    const float* __restrict__ bias, float* __restrict__ outf,
    u16* __restrict__ outb, int ldc)
{
  size_t i0 = (size_t)blockIdx.y * 128, j0 = (size_t)blockIdx.x * 128;
  mfma_tile(A + i0*K, B + j0*K, K,
            bias ? bias + j0 : nullptr,
            outf ? outf + i0*ldc + j0 : nullptr,
            outb ? outb + i0*ldc + j0 : nullptr, ldc);
}

// ---------------- 64x64-tile NT GEMM (16 KB LDS, for skinny/parallel shapes) ----------------
__global__ __launch_bounds__(256) void k_mfma64(
    const u16* __restrict__ Ag, const u16* __restrict__ Bg, int K,
    int clamp1, u16* __restrict__ outb, int ldc)
{
  __shared__ u16 ldsA[64*64];
  __shared__ u16 ldsB[64*64];
  const int tid  = threadIdx.x;
  const int lane = tid & 63;
  const int w    = tid >> 6;
  const int wr   = (w >> 1) * 32;
  const int wc   = (w & 1) * 32;
  const u16* A = Ag + (size_t)blockIdx.y*64*K;
  const u16* B = Bg + (size_t)blockIdx.x*64*K;
  f32x4 acc[2][2] = {};

  const int lrow = lane >> 3;
  const int srck = ((lane & 7) ^ lrow) * 8;
  for (int k0 = 0; k0 < K; k0 += 64){
    #pragma unroll
    for (int c = 0; c < 2; ++c){
      int row = w*16 + c*8;
      GLD16(A + (size_t)(row + lrow)*K + k0 + srck, &ldsA[row*64]);
      GLD16(B + (size_t)(row + lrow)*K + k0 + srck, &ldsB[row*64]);
    }
    __syncthreads();
    #pragma unroll
    for (int kk = 0; kk < 2; ++kk){
      bf16x8 af[2], bfr[2];
      #pragma unroll
      for (int mi = 0; mi < 2; ++mi){
        int row = wr + mi*16 + (lane & 15);
        int grp = (kk*4 + (lane >> 4)) ^ (row & 7);
        af[mi] = *(const bf16x8*)&ldsA[row*64 + grp*8];
      }
      #pragma unroll
      for (int ni = 0; ni < 2; ++ni){
        int row = wc + ni*16 + (lane & 15);
        int grp = (kk*4 + (lane >> 4)) ^ (row & 7);
        bfr[ni] = *(const bf16x8*)&ldsB[row*64 + grp*8];
      }
      #pragma unroll
      for (int mi = 0; mi < 2; ++mi)
        #pragma unroll
        for (int ni = 0; ni < 2; ++ni)
          acc[mi][ni] = __builtin_amdgcn_mfma_f32_16x16x32_bf16(af[mi], bfr[ni], acc[mi][ni], 0, 0, 0);
    }
    __syncthreads();
  }
  #pragma unroll
  for (int mi = 0; mi < 2; ++mi){
    #pragma unroll
    for (int ni = 0; ni < 2; ++ni){
      int col = blockIdx.x*64 + wc + ni*16 + (lane & 15);
      #pragma unroll
      for (int q = 0; q < 4; ++q){
        int row = blockIdx.y*64 + wr + mi*16 + (lane >> 4)*4 + q;
        float v = acc[mi][ni][q];
        if (clamp1) v = fminf(v, 1.f);
        outb[(size_t)row*ldc + col] = f2b(v);
      }
    }
  }
}

// ---------------- fused per-step kernel ----------------
// 1024 blocks x 256 thr: job = bid>>9; rem = bid&511; s = rem>>1 (4 gate cells); r0 = (rem&1)*64.
// GEMM M=64, N=16 (4 segs x 4 cells packed), K=1024 over H_prev, BK=128 single-buffer.
__global__ __launch_bounds__(256) void k_step(
    const u16* __restrict__ WgHp, const u16* __restrict__ rWgHp,
    const u16* __restrict__ pre_t,           // [BC][8192] bf16; job*4096 col offset
    const float* __restrict__ nbrv,
    u16* __restrict__ Hb2, u16* __restrict__ rHb2,
    float* __restrict__ Cs, float* __restrict__ rCs,
    float* __restrict__ Hf, float* __restrict__ rHf,
    int ph, int last)
{
  __shared__ u16 ldsA[64*128];   // 16 KB
  __shared__ u16 ldsB[16*128];   // 4 KB

  const int tid  = threadIdx.x;
  const int lane = tid & 63;
  const int w    = tid >> 6;          // 0..3
  const int bid  = blockIdx.x;
  const int job  = bid >> 9;
  const int rem  = bid & 511;
  const int s    = rem >> 1;
  const int r0   = (rem & 1) * 64;

  const u16* Bp   = (job ? rWgHp : WgHp) + (size_t)s*16*1024;
  const u16* Ab   = (job ? rHb2 : Hb2) + (size_t)ph*BC*NN + (size_t)r0*NN;
  const u16* pret = pre_t + (size_t)job*4096;
  u16* Hnext  = (job ? rHb2 : Hb2) + (size_t)(ph^1)*BC*NN;
  float* Csb  = job ? rCs : Cs;
  float* Hfin = job ? rHf : Hf;

  const int lrow = lane >> 4;          // 0..3 (4 rows per GLD16 at 128 cols)
  const int s4   = lane & 15;

  f32x4 acc = {};
  for (int t = 0; t < 8; ++t){
    int k0 = t*128;
    #pragma unroll
    for (int c = 0; c < 4; ++c){
      int rowb = w*16 + c*4;
      int row = rowb + lrow;
      int srcg = (s4 & 8) | ((s4 & 7) ^ (row & 7));
      GLD16(Ab + (size_t)row*1024 + k0 + srcg*8, &ldsA[rowb*128]);
    }
    { int rowb = w*4;
      int row = rowb + lrow;
      int srcg = (s4 & 8) | ((s4 & 7) ^ (row & 7));
      GLD16(Bp + (size_t)row*1024 + k0 + srcg*8, &ldsB[rowb*128]); }
    __syncthreads();
    #pragma unroll
    for (int kk = 0; kk < 4; ++kk){
      int idx = kk*4 + (lane >> 4);
      int rowa = w*16 + (lane & 15);
      int pa = (idx & 8) | ((idx & 7) ^ (rowa & 7));
      bf16x8 af = *(const bf16x8*)&ldsA[rowa*128 + pa*8];
      int rowb2 = lane & 15;
      int pb = (idx & 8) | ((idx & 7) ^ (rowb2 & 7));
      bf16x8 bv = *(const bf16x8*)&ldsB[rowb2*128 + pb*8];
      acc = __builtin_amdgcn_mfma_f32_16x16x32_bf16(af, bv, acc, 0, 0, 0);
    }
    __syncthreads();
  }

  // epilogue: + pre, gates via shfl_xor(4/8/12), Cs update
  const int pcol = lane & 15;               // seg = pcol>>2, cc = pcol&3
  const int gcol = (pcol >> 2)*1024 + s*4 + (pcol & 3);
  const bool act = (lane & 12) == 0;        // seg 0 lanes
  const int  col = s*4 + (lane & 3);
  float fac = 1.f;
  if (!job && act) fac = nbrv[col];
  #pragma unroll
  for (int q = 0; q < 4; ++q){
    int row = r0 + w*16 + (lane >> 4)*4 + q;
    float a = acc[q] + b2f(pret[(size_t)row*8192 + gcol]);
    float vi  = __shfl_xor(a, 4);
    float vo  = __shfl_xor(a, 8);
    float vct = __shfl_xor(a, 12);
    if (act){
      float fg = sigf(a), ig = sigf(vi), og = sigf(vo), ct = tanhf(vct);
      size_t cidx = (size_t)row*NN + col;
      float cs = fg*Csb[cidx]*fac + ig*ct;
      Csb[cidx] = cs;
      float h = og*tanhf(cs);
      Hnext[cidx] = f2b(h);
      if (last) Hfin[cidx] = h;
    }
  }
}

// ---------------- last-step statistics (two-stage) ----------------
__global__ void k_var1(const u16* __restrict__ Xl, const u16* __restrict__ gcl,
                       float* __restrict__ part){
  int ch = blockIdx.x & 1, seg = blockIdx.x >> 1;   // 64 blocks
  int tid = threadIdx.x;
  float s1=0.f,q1=0.f,s2=0.f,q2=0.f;
  for (int bb = 0; bb < 2; ++bb){
    int row = (seg*2+bb)*2 + ch;
    const u16* xr = Xl + (size_t)row*1024;
    for (int n = tid; n < 1024; n += 256){ float v = b2f(xr[n]); s1 += v; q1 += v*v; }
    const u16* gr = gcl + (size_t)row*3072;
    for (int n = tid; n < 3072; n += 256){ float v = b2f(gr[n]); s2 += v; q2 += v*v; }
  }
  __shared__ float red[256][4];
  red[tid][0]=s1; red[tid][1]=q1; red[tid][2]=s2; red[tid][3]=q2;
  __syncthreads();
  for (int st = 128; st > 0; st >>= 1){
    if (tid < st){ for (int z = 0; z < 4; ++z) red[tid][z] += red[tid+st][z]; }
    __syncthreads();
  }
  if (tid == 0){ for (int z = 0; z < 4; ++z) part[(size_t)blockIdx.x*4 + z] = red[0][z]; }
}
__global__ void k_var2(const float* __restrict__ part, float* __restrict__ vars){
  int tid = threadIdx.x;
  if (tid < 2){
    float s1=0.f,q1=0.f,s2=0.f,q2=0.f;
    for (int seg = 0; seg < 32; ++seg){
      const float* p = part + (size_t)(seg*2+tid)*4;
      s1 += p[0]; q1 += p[1]; s2 += p[2]; q2 += p[3];
    }
    float n1 = 65536.f, n2 = 196608.f;
    vars[tid]   = (q1 - s1*s1/n1) / (n1 - 1.f);
    vars[2+tid] = (q2 - s2*s2/n2) / (n2 - 1.f);
  }
}

// fused pred + conv: one thread per (b,n)
__global__ void k_out(const float* __restrict__ H, const float* __restrict__ rH,
                      const float* __restrict__ vars, const float* __restrict__ cptr,
                      const float* __restrict__ cw, const float* __restrict__ cb,
                      float* __restrict__ out){
  int idx = blockIdx.x*256 + threadIdx.x;   // 64*1024
  int n = idx & 1023, b = idx >> 10;
  float c0 = cptr[0];
  float v10 = vars[0], v11 = vars[1], v20 = vars[2], v21 = vars[3];
  size_t i0 = (size_t)(b*2+0)*1024 + n, i1 = (size_t)(b*2+1)*1024 + n;
  float p0 = (H[i0]*v10*c0 + rH[i0]*v20) / (v10 + v20*c0);
  float p1 = (H[i1]*v11*c0 + rH[i1]*v21) / (v11 + v21*c0);
  float* ob = out + (size_t)b*24*1024 + n;
  #pragma unroll
  for (int o = 0; o < 24; ++o)
    ob[(size_t)o*1024] = p0*cw[o*2+0] + p1*cw[o*2+1] + cb[o];
}

// ---------------- launch ----------------
extern "C" void kernel_launch(void* const* d_in, const int* in_sizes, int n_in,
                              void* d_out, int out_size, void* d_ws, size_t ws_size,
                              hipStream_t stream) {
  const float* inputs = (const float*)d_in[0];
  const float* adj    = (const float*)d_in[1];
  const float* gcw    = (const float*)d_in[2];
  const float* Wf  = (const float*)d_in[3];  const float* bf_ = (const float*)d_in[4];
  const float* Wi  = (const float*)d_in[5];  const float* bi_ = (const float*)d_in[6];
  const float* Wo  = (const float*)d_in[7];  const float* bo_ = (const float*)d_in[8];
  const float* Wc  = (const float*)d_in[9];  const float* bc_ = (const float*)d_in[10];
  const float* rWf = (const float*)d_in[11]; const float* rbf = (const float*)d_in[12];
  const float* rWi = (const float*)d_in[13]; const float* rbi = (const float*)d_in[14];
  const float* rWo = (const float*)d_in[15]; const float* rbo = (const float*)d_in[16];
  const float* rWc = (const float*)d_in[17]; const float* rbc = (const float*)d_in[18];
  const float* nw     = (const float*)d_in[19];
  const float* cscal  = (const float*)d_in[20];
  const float* convw  = (const float*)d_in[21];
  const float* convb  = (const float*)d_in[22];
  float* out = (float*)d_out;

  char* cur = (char*)d_ws;
  auto alloc = [&](size_t bytes) -> void* {
    void* p = cur; cur += (bytes + 255) & ~(size_t)255; return p;
  };
  u16*   Xb     = (u16*)  alloc((size_t)LS*BC*NN*2);      // 6 MB
  float* csum   = (float*)alloc((size_t)64*1024*4);
  float* tmpv   = (float*)alloc(1024*4);
  u16*   anormT = (u16*)  alloc((size_t)NN*NN*2);         // 2 MB
  u16*   Apowb  = (u16*)  alloc((size_t)3*NN*NN*2);       // 6 MB
  float* nbrv   = (float*)alloc(1024*4);
  u16*   effb   = (u16*)  alloc((size_t)3*NN*NN*2);       // 6 MB
  u16*   effbT  = (u16*)  alloc((size_t)3*NN*NN*2);       // 6 MB
  u16*   Wgxb   = (u16*)  alloc((size_t)4096*3072*2);     // 24 MB
  u16*   WgHp   = (u16*)  alloc((size_t)4096*1024*2);     // 8 MB
  u16*   rWgHp  = (u16*)  alloc((size_t)4096*1024*2);     // 8 MB
  u16*   Bcat   = (u16*)  alloc((size_t)8192*1024*2);     // 16 MB: [Cw; rWgx]
  float* bgcat  = (float*)alloc(8192*4);
  u16*   gclb   = (u16*)  alloc((size_t)BC*3072*2);
  u16*   prebuf = (u16*)  alloc((size_t)3072*8192*2);     // 48 MB bf16
  char*  zbase  = cur;
  u16*   Hb2    = (u16*)  alloc((size_t)2*BC*NN*2);
  u16*   rHb2   = (u16*)  alloc((size_t)2*BC*NN*2);
  float* Cs     = (float*)alloc((size_t)BC*NN*4);
  float* rCs    = (float*)alloc((size_t)BC*NN*4);
  size_t zlen   = (size_t)(cur - zbase);
  float* Hfv    = (float*)alloc((size_t)BC*NN*4);
  float* rHfv   = (float*)alloc((size_t)BC*NN*4);
  float* vars   = (float*)alloc(16*4);
  float* part   = (float*)alloc(64*4*4);

  u16* A1b = Apowb;
  u16* A2b = Apowb + (size_t)NN*NN;
  u16* A3b = Apowb + (size_t)2*NN*NN;
  u16* Cwb   = Bcat;                       // rows 0..4095
  u16* rWgxb = Bcat + (size_t)4096*1024;   // rows 4096..8191

  // preprocessing
  k_transpose<<<(BC*NN)/256, 256, 0, stream>>>(inputs, Xb);
  k_colsum1<<<64, 256, 0, stream>>>(adj, csum);
  k_colsum2<<<4, 256, 0, stream>>>(csum, tmpv);
  dim3 g16(16, 16);
  k_anormT<<<g16, 256, 0, stream>>>(adj, tmpv, A1b, anormT);
  // adjacency powers, 64^2 tiles (256 blocks each)
  k_mfma64<<<g16, 256, 0, stream>>>(A1b, anormT, 1024, 1, A2b, 1024);
  k_mfma64<<<g16, 256, 0, stream>>>(A2b, anormT, 1024, 1, A3b, 1024);
  k_nbr<<<NN, 256, 0, stream>>>(A3b, nw, nbrv);
  dim3 geff(16, 48);
  k_effT<<<geff, 256, 0, stream>>>(Apowb, gcw, effb, effbT);
  k_pack<<<(16777216+8388608)/256, 256, 0, stream>>>(Wf, Wi, Wo, Wc, rWf, rWi, rWo, rWc,
                                                     Wgxb, WgHp, rWgxb, rWgHp);
  k_packbias<<<16, 256, 0, stream>>>(bf_, bi_, bo_, bc_, rbf, rbi, rbo, rbc,
                                     bgcat, bgcat + 4096);

  // Cw = Wgx @ eff (4096x1024, K=3072), 64^2 tiles -> 1024 blocks
  dim3 gcwg(16, 64);
  k_mfma64<<<gcwg, 256, 0, stream>>>(Wgxb, effbT, 3072, 0, Cwb, 1024);
  // pre = X @ [Cw; rWgx]^T + biascat (3072x8192, K=1024), bf16 out, 128^2 tiles
  dim3 gpre(64, 24);
  k_mfma_nt<<<gpre, 256, 0, stream>>>(Xb, Bcat, 1024, bgcat, nullptr, prebuf, 8192);
  // last-step gc (for var only), 64^2 tiles -> 96 blocks
  dim3 ggcl(48, 2);
  k_mfma64<<<ggcl, 256, 0, stream>>>(Xb + (size_t)(LS-1)*BC*NN, effb, 1024, 0, gclb, 3072);

  hipMemsetAsync(zbase, 0, zlen, stream);

  // 24 fused steps
  for (int t = 0; t < LS; ++t)
    k_step<<<1024, 256, 0, stream>>>(WgHp, rWgHp,
        prebuf + (size_t)t*BC*8192,
        nbrv, Hb2, rHb2, Cs, rCs, Hfv, rHfv, t & 1, t == LS-1);

  k_var1<<<64, 256, 0, stream>>>(Xb + (size_t)(LS-1)*BC*NN, gclb, part);
  k_var2<<<1, 64, 0, stream>>>(part, vars);
  k_out<<<(64*1024)/256, 256, 0, stream>>>(Hfv, rHfv, vars, cscal, convw, convb, out);
}

// Round 7
// 617.576 us; speedup vs baseline: 4.7422x; 1.0018x over previous
//
#include <hip/hip_runtime.h>
#include <cmath>

#define NN 1024
#define BC 128
#define LS 24

typedef unsigned short u16;
typedef __attribute__((ext_vector_type(4))) float f32x4;
typedef __attribute__((ext_vector_type(8))) short bf16x8;

typedef __attribute__((address_space(1))) const void* as1cv;
typedef __attribute__((address_space(3))) void* as3v;

#define GLD16(gp, lp) __builtin_amdgcn_global_load_lds((as1cv)(gp), (as3v)(lp), 16, 0, 0)

__device__ __forceinline__ float sigf(float x){ return 1.0f/(1.0f+expf(-x)); }

__device__ __forceinline__ u16 f2b(float x){
  union { float f; unsigned u; } v; v.f = x;
  unsigned r = v.u + 0x7FFFu + ((v.u >> 16) & 1u);
  return (u16)(r >> 16);
}
__device__ __forceinline__ float b2f(u16 b){
  union { unsigned u; float f; } v; v.u = ((unsigned)b) << 16;
  return v.f;
}

// ---------------- fused preprocessing (independent parts) ----------------
// blocks [0,512): transpose; [512,576): colsum1; [576,592): packbias; [592,...): pack
__global__ void k_prep(const float* __restrict__ inputs, const float* __restrict__ adj,
                       const float* __restrict__ Wf, const float* __restrict__ Wi,
                       const float* __restrict__ Wo, const float* __restrict__ Wc,
                       const float* __restrict__ rWf, const float* __restrict__ rWi,
                       const float* __restrict__ rWo, const float* __restrict__ rWc,
                       const float* __restrict__ bf_, const float* __restrict__ bi_,
                       const float* __restrict__ bo_, const float* __restrict__ bc_,
                       const float* __restrict__ rbf, const float* __restrict__ rbi,
                       const float* __restrict__ rbo, const float* __restrict__ rbc,
                       u16* __restrict__ Xb, float* __restrict__ csum,
                       u16* __restrict__ Wgxb, u16* __restrict__ WgHp,
                       u16* __restrict__ rWgxb, u16* __restrict__ rWgHp,
                       float* __restrict__ bgcat){
  int b = blockIdx.x, tid = threadIdx.x;
  if (b < 512){
    int idx = b*256 + tid;                       // BC*NN
    const float4* p = (const float4*)(inputs + (size_t)idx*LS);
    float v[LS];
    #pragma unroll
    for (int q = 0; q < 6; ++q){
      float4 f = p[q];
      v[q*4]=f.x; v[q*4+1]=f.y; v[q*4+2]=f.z; v[q*4+3]=f.w;
    }
    #pragma unroll
    for (int t = 0; t < LS; ++t)
      Xb[(size_t)t*BC*NN + idx] = f2b(v[t]);
  } else if (b < 576){
    int bb = b - 512;
    for (int j = tid; j < 1024; j += 256){
      float s = 0.f;
      for (int i = 0; i < 16; ++i) s += adj[(size_t)(bb*16+i)*1024 + j];
      csum[(size_t)bb*1024 + j] = s;
    }
  } else if (b < 592){
    int idx = (b-576)*256 + tid;                 // 4096
    int seg = idx >> 10, j = idx & 1023;
    bgcat[idx]      = (seg==0?bf_: seg==1?bi_: seg==2?bo_:bc_)[j];
    bgcat[4096+idx] = (seg==0?rbf: seg==1?rbi: seg==2?rbo:rbc)[j];
  } else {
    int idx = (b-592)*256 + tid;
    if (idx < 16777216){
      int k = idx & 4095, r = idx >> 12, seg = r >> 10, j = r & 1023;
      const float* W = seg==0?Wf: seg==1?Wi: seg==2?Wo:Wc;
      float v = W[(size_t)j*4096 + k];
      if (k < 3072) Wgxb[(size_t)r*3072 + k] = f2b(v);
      else {
        int p = (j>>2)*16 + seg*4 + (j&3);
        WgHp[(size_t)p*1024 + (k-3072)] = f2b(v);
      }
    } else {
      int i2 = idx - 16777216;
      int k = i2 & 2047, r = i2 >> 11, seg = r >> 10, j = r & 1023;
      const float* W = seg==0?rWf: seg==1?rWi: seg==2?rWo:rWc;
      float v = W[(size_t)j*2048 + k];
      if (k < 1024) rWgxb[(size_t)r*1024 + k] = f2b(v);
      else {
        int p = (j>>2)*16 + seg*4 + (j&3);
        rWgHp[(size_t)p*1024 + (k-1024)] = f2b(v);
      }
    }
  }
}

__global__ void k_colsum2(const float* __restrict__ part, float* __restrict__ tmp){
  int j = blockIdx.x*256 + threadIdx.x;
  float s = 0.f;
  for (int b = 0; b < 64; ++b) s += part[(size_t)b*1024 + j];
  tmp[j] = (s == 0.f) ? 1e-5f : s;
}

// fused: A1b = bf16(min(tmp[i]*adj,1)); anormT = bf16(tmp[i]*adj)^T
__global__ void k_anormT(const float* __restrict__ adj, const float* __restrict__ tmp,
                         u16* __restrict__ A1b, u16* __restrict__ anormT){
  __shared__ u16 t[64][65];
  int bi = blockIdx.y*64, bj = blockIdx.x*64;
  for (int e = threadIdx.x; e < 4096; e += 256){
    int r = e >> 6, cc = e & 63;
    float v = tmp[bi+r]*adj[(size_t)(bi+r)*1024 + bj+cc];
    A1b[(size_t)(bi+r)*1024 + bj+cc] = f2b(fminf(v, 1.f));
    t[r][cc] = f2b(v);
  }
  __syncthreads();
  for (int e = threadIdx.x; e < 4096; e += 256){
    int r = e >> 6, cc = e & 63;
    anormT[(size_t)(bj+r)*1024 + bi+cc] = t[cc][r];
  }
}

__global__ void k_nbr(const u16* __restrict__ A3b, const float* __restrict__ nw,
                      float* __restrict__ nbr){
  __shared__ float red[256];
  int row = blockIdx.x;
  float s = 0.f;
  for (int j = threadIdx.x; j < 1024; j += 256)
    s += b2f(A3b[(size_t)row*1024 + j])*nw[j];
  red[threadIdx.x] = s; __syncthreads();
  for (int st = 128; st > 0; st >>= 1){
    if (threadIdx.x < st) red[threadIdx.x] += red[threadIdx.x+st];
    __syncthreads();
  }
  if (threadIdx.x == 0) nbr[row] = red[0];
}

__global__ void k_effT(const u16* __restrict__ Ap, const float* __restrict__ gcw,
                       u16* __restrict__ effb, u16* __restrict__ effbT){
  __shared__ u16 t[64][65];
  int bi = blockIdx.y*64, bj = blockIdx.x*64;   // bi over 3072, bj over 1024
  for (int e = threadIdx.x; e < 4096; e += 256){
    int r = e >> 6, cc = e & 63;
    size_t idx = (size_t)(bi+r)*1024 + bj+cc;
    u16 v = f2b(b2f(Ap[idx]) * gcw[idx]);
    effb[idx] = v;
    t[r][cc] = v;
  }
  __syncthreads();
  for (int e = threadIdx.x; e < 4096; e += 256){
    int r = e >> 6, cc = e & 63;
    effbT[(size_t)(bj+r)*3072 + bi+cc] = t[cc][r];
  }
}

// ---------------- bf16 MFMA NT GEMM, 128x128 tile (m97 structure) ----------------
__device__ __forceinline__ void stage128(const u16* __restrict__ A, const u16* __restrict__ B,
                                         int K, int k0, u16* lA, u16* lB, int w, int lane){
  const int lrow = lane >> 3;
  const int srck = ((lane & 7) ^ lrow) * 8;
  #pragma unroll
  for (int c = 0; c < 4; ++c){
    int row = w*32 + c*8;
    GLD16(A + (size_t)(row + lrow)*K + k0 + srck, &lA[row*64]);
    GLD16(B + (size_t)(row + lrow)*K + k0 + srck, &lB[row*64]);
  }
}

__device__ __forceinline__ void mfma_tile(
    const u16* __restrict__ A, const u16* __restrict__ Bw, int K,
    const float* __restrict__ bias,
    float* __restrict__ outf, u16* __restrict__ outb, int ldc)
{
  __shared__ u16 ldsA[128*64];
  __shared__ u16 ldsB[128*64];
  const int tid  = threadIdx.x;
  const int lane = tid & 63;
  const int w    = tid >> 6;
  const int wr   = (w >> 1) * 64;
  const int wc   = (w & 1) * 64;
  f32x4 acc[4][4] = {};

  for (int k0 = 0; k0 < K; k0 += 64){
    stage128(A, Bw, K, k0, ldsA, ldsB, w, lane);
    __syncthreads();
    #pragma unroll
    for (int kk = 0; kk < 2; ++kk) {
      bf16x8 af[4], bfr[4];
      #pragma unroll
      for (int mi = 0; mi < 4; ++mi) {
        int row = wr + mi*16 + (lane & 15);
        int grp = (kk*4 + (lane >> 4)) ^ (row & 7);
        af[mi] = *(const bf16x8*)&ldsA[row*64 + grp*8];
      }
      #pragma unroll
      for (int ni = 0; ni < 4; ++ni) {
        int row = wc + ni*16 + (lane & 15);
        int grp = (kk*4 + (lane >> 4)) ^ (row & 7);
        bfr[ni] = *(const bf16x8*)&ldsB[row*64 + grp*8];
      }
      #pragma unroll
      for (int mi = 0; mi < 4; ++mi)
        #pragma unroll
        for (int ni = 0; ni < 4; ++ni)
          acc[mi][ni] = __builtin_amdgcn_mfma_f32_16x16x32_bf16(af[mi], bfr[ni], acc[mi][ni], 0, 0, 0);
    }
    __syncthreads();
  }
  #pragma unroll
  for (int mi = 0; mi < 4; ++mi) {
    #pragma unroll
    for (int ni = 0; ni < 4; ++ni) {
      int col = wc + ni*16 + (lane & 15);
      #pragma unroll
      for (int q = 0; q < 4; ++q) {
        int row = wr + mi*16 + (lane >> 4)*4 + q;
        float v = acc[mi][ni][q];
        if (bias) v += bias[col];
        if (outf) outf[(size_t)row*ldc + col] = v;
        if (outb) outb[(size_t)row*ldc + col] = f2b(v);
      }
    }
  }
}

__global__ __launch_bounds__(256) void k_mfma_nt(
    const u16* __restrict__ A, const u16* __restrict__ B, int K,
    const float* __restrict__ bias, float* __restrict__ outf,
    u16* __restrict__ outb, int ldc)
{
  size_t i0 = (size_t)blockIdx.y * 128, j0 = (size_t)blockIdx.x * 128;
  mfma_tile(A + i0*K, B + j0*K, K,
            bias ? bias + j0 : nullptr,
            outf ? outf + i0*ldc + j0 : nullptr,
            outb ? outb + i0*ldc + j0 : nullptr, ldc);
}

// ---------------- 64x64-tile NT GEMM, BK=128 (32 KB LDS) ----------------
__global__ __launch_bounds__(256) void k_mfma64(
    const u16* __restrict__ Ag, const u16* __restrict__ Bg, int K,
    int clamp1, u16* __restrict__ outb, int ldc)
{
  __shared__ u16 ldsA[64*128];   // 16 KB
  __shared__ u16 ldsB[64*128];   // 16 KB
  const int tid  = threadIdx.x;
  const int lane = tid & 63;
  const int w    = tid >> 6;
  const int wr   = (w >> 1) * 32;
  const int wc   = (w & 1) * 32;
  const u16* A = Ag + (size_t)blockIdx.y*64*K;
  const u16* B = Bg + (size_t)blockIdx.x*64*K;
  f32x4 acc[2][2] = {};

  const int r4  = lane >> 4;           // 0..3 row offset within issue
  const int g16 = lane & 15;           // 16B group within row
  for (int k0 = 0; k0 < K; k0 += 128){
    #pragma unroll
    for (int c = 0; c < 4; ++c){
      int rowb = w*16 + c*4;
      int row = rowb + r4;
      int srcg = (g16 & 8) | ((g16 & 7) ^ (row & 7));
      GLD16(A + (size_t)row*K + k0 + srcg*8, &ldsA[rowb*128]);
      GLD16(B + (size_t)row*K + k0 + srcg*8, &ldsB[rowb*128]);
    }
    __syncthreads();
    #pragma unroll
    for (int kk = 0; kk < 4; ++kk){
      int idx = kk*4 + (lane >> 4);
      bf16x8 af[2], bfr[2];
      #pragma unroll
      for (int mi = 0; mi < 2; ++mi){
        int row = wr + mi*16 + (lane & 15);
        int pa = (idx & 8) | ((idx & 7) ^ (row & 7));
        af[mi] = *(const bf16x8*)&ldsA[row*128 + pa*8];
      }
      #pragma unroll
      for (int ni = 0; ni < 2; ++ni){
        int row = wc + ni*16 + (lane & 15);
        int pb = (idx & 8) | ((idx & 7) ^ (row & 7));
        bfr[ni] = *(const bf16x8*)&ldsB[row*128 + pb*8];
      }
      #pragma unroll
      for (int mi = 0; mi < 2; ++mi)
        #pragma unroll
        for (int ni = 0; ni < 2; ++ni)
          acc[mi][ni] = __builtin_amdgcn_mfma_f32_16x16x32_bf16(af[mi], bfr[ni], acc[mi][ni], 0, 0, 0);
    }
    __syncthreads();
  }
  #pragma unroll
  for (int mi = 0; mi < 2; ++mi){
    #pragma unroll
    for (int ni = 0; ni < 2; ++ni){
      int col = blockIdx.x*64 + wc + ni*16 + (lane & 15);
      #pragma unroll
      for (int q = 0; q < 4; ++q){
        int row = blockIdx.y*64 + wr + mi*16 + (lane >> 4)*4 + q;
        float v = acc[mi][ni][q];
        if (clamp1) v = fminf(v, 1.f);
        outb[(size_t)row*ldc + col] = f2b(v);
      }
    }
  }
}

// ---------------- fused per-step kernel, BK=256 (4 chunks) ----------------
// 1024 blocks x 256 thr: job = bid>>9; rem = bid&511; s = rem>>1; r0 = (rem&1)*64.
// GEMM M=64, N=16 (4 segs x 4 cells packed), K=1024 over H_prev.
__global__ __launch_bounds__(256) void k_step(
    const u16* __restrict__ WgHp, const u16* __restrict__ rWgHp,
    const u16* __restrict__ pre_t,           // [BC][8192] bf16; job*4096 col offset
    const float* __restrict__ nbrv,
    u16* __restrict__ Hb2, u16* __restrict__ rHb2,
    float* __restrict__ Cs, float* __restrict__ rCs,
    float* __restrict__ Hf, float* __restrict__ rHf,
    int ph, int last)
{
  __shared__ u16 ldsA[64*256];   // 32 KB
  __shared__ u16 ldsB[16*256];   // 8 KB

  const int tid  = threadIdx.x;
  const int lane = tid & 63;
  const int w    = tid >> 6;          // 0..3
  const int bid  = blockIdx.x;
  const int job  = bid >> 9;
  const int rem  = bid & 511;
  const int s    = rem >> 1;
  const int r0   = (rem & 1) * 64;

  const u16* Bp   = (job ? rWgHp : WgHp) + (size_t)s*16*1024;
  const u16* Ab   = (job ? rHb2 : Hb2) + (size_t)ph*BC*NN + (size_t)r0*NN;
  const u16* pret = pre_t + (size_t)job*4096;
  u16* Hnext  = (job ? rHb2 : Hb2) + (size_t)(ph^1)*BC*NN;
  float* Csb  = job ? rCs : Cs;
  float* Hfin = job ? rHf : Hf;

  const int g32   = lane & 31;       // 16B group within 512B row
  const int rhalf = lane >> 5;       // 0..1 row offset within issue

  f32x4 acc = {};
  for (int t = 0; t < 4; ++t){
    int k0 = t*256;
    #pragma unroll
    for (int c = 0; c < 8; ++c){
      int rowb = w*16 + c*2;
      int row = rowb + rhalf;
      int srcg = (g32 & 24) | ((g32 & 7) ^ (row & 7));
      GLD16(Ab + (size_t)row*1024 + k0 + srcg*8, &ldsA[rowb*256]);
    }
    #pragma unroll
    for (int c = 0; c < 2; ++c){
      int rowb = w*4 + c*2;
      int row = rowb + rhalf;
      int srcg = (g32 & 24) | ((g32 & 7) ^ (row & 7));
      GLD16(Bp + (size_t)row*1024 + k0 + srcg*8, &ldsB[rowb*256]);
    }
    __syncthreads();
    #pragma unroll
    for (int kk = 0; kk < 8; ++kk){
      int idx = kk*4 + (lane >> 4);
      int rowa = w*16 + (lane & 15);
      int pa = (idx & 24) | ((idx & 7) ^ (rowa & 7));
      bf16x8 af = *(const bf16x8*)&ldsA[rowa*256 + pa*8];
      int rowb2 = lane & 15;
      int pb = (idx & 24) | ((idx & 7) ^ (rowb2 & 7));
      bf16x8 bv = *(const bf16x8*)&ldsB[rowb2*256 + pb*8];
      acc = __builtin_amdgcn_mfma_f32_16x16x32_bf16(af, bv, acc, 0, 0, 0);
    }
    __syncthreads();
  }

  // epilogue: + pre, gates via shfl_xor(4/8/12), Cs update
  const int pcol = lane & 15;               // seg = pcol>>2, cc = pcol&3
  const int gcol = (pcol >> 2)*1024 + s*4 + (pcol & 3);
  const bool act = (lane & 12) == 0;        // seg 0 lanes
  const int  col = s*4 + (lane & 3);
  float fac = 1.f;
  if (!job && act) fac = nbrv[col];
  #pragma unroll
  for (int q = 0; q < 4; ++q){
    int row = r0 + w*16 + (lane >> 4)*4 + q;
    float a = acc[q] + b2f(pret[(size_t)row*8192 + gcol]);
    float vi  = __shfl_xor(a, 4);
    float vo  = __shfl_xor(a, 8);
    float vct = __shfl_xor(a, 12);
    if (act){
      float fg = sigf(a), ig = sigf(vi), og = sigf(vo), ct = tanhf(vct);
      size_t cidx = (size_t)row*NN + col;
      float cs = fg*Csb[cidx]*fac + ig*ct;
      Csb[cidx] = cs;
      float h = og*tanhf(cs);
      Hnext[cidx] = f2b(h);
      if (last) Hfin[cidx] = h;
    }
  }
}

// ---------------- last-step statistics ----------------
__global__ void k_var1(const u16* __restrict__ Xl, const u16* __restrict__ gcl,
                       float* __restrict__ part){
  int ch = blockIdx.x & 1, seg = blockIdx.x >> 1;   // 64 blocks
  int tid = threadIdx.x;
  float s1=0.f,q1=0.f,s2=0.f,q2=0.f;
  for (int bb = 0; bb < 2; ++bb){
    int row = (seg*2+bb)*2 + ch;
    const u16* xr = Xl + (size_t)row*1024;
    for (int n = tid; n < 1024; n += 256){ float v = b2f(xr[n]); s1 += v; q1 += v*v; }
    const u16* gr = gcl + (size_t)row*3072;
    for (int n = tid; n < 3072; n += 256){ float v = b2f(gr[n]); s2 += v; q2 += v*v; }
  }
  __shared__ float red[256][4];
  red[tid][0]=s1; red[tid][1]=q1; red[tid][2]=s2; red[tid][3]=q2;
  __syncthreads();
  for (int st = 128; st > 0; st >>= 1){
    if (tid < st){ for (int z = 0; z < 4; ++z) red[tid][z] += red[tid+st][z]; }
    __syncthreads();
  }
  if (tid == 0){ for (int z = 0; z < 4; ++z) part[(size_t)blockIdx.x*4 + z] = red[0][z]; }
}

// fused var2 + pred + conv: one thread per (b,n), 256 blocks
__global__ void k_out(const float* __restrict__ H, const float* __restrict__ rH,
                      const float* __restrict__ part, const float* __restrict__ cptr,
                      const float* __restrict__ cw, const float* __restrict__ cb,
                      float* __restrict__ out){
  __shared__ float vsh[4];
  int tid = threadIdx.x;
  if (tid < 4){
    int ch = tid & 1, which = tid >> 1;   // which: 0=var1, 1=var2
    float s = 0.f, q = 0.f;
    for (int seg = 0; seg < 32; ++seg){
      const float* p = part + (size_t)(seg*2+ch)*4 + which*2;
      s += p[0]; q += p[1];
    }
    float n = which ? 196608.f : 65536.f;
    vsh[tid] = (q - s*s/n) / (n - 1.f);
  }
  __syncthreads();
  int idx = blockIdx.x*256 + tid;   // 64*1024
  int n = idx & 1023, b = idx >> 10;
  float c0 = cptr[0];
  float v10 = vsh[0], v11 = vsh[1], v20 = vsh[2], v21 = vsh[3];
  size_t i0 = (size_t)(b*2+0)*1024 + n, i1 = (size_t)(b*2+1)*1024 + n;
  float p0 = (H[i0]*v10*c0 + rH[i0]*v20) / (v10 + v20*c0);
  float p1 = (H[i1]*v11*c0 + rH[i1]*v21) / (v11 + v21*c0);
  float* ob = out + (size_t)b*24*1024 + n;
  #pragma unroll
  for (int o = 0; o < 24; ++o)
    ob[(size_t)o*1024] = p0*cw[o*2+0] + p1*cw[o*2+1] + cb[o];
}

// ---------------- launch ----------------
extern "C" void kernel_launch(void* const* d_in, const int* in_sizes, int n_in,
                              void* d_out, int out_size, void* d_ws, size_t ws_size,
                              hipStream_t stream) {
  const float* inputs = (const float*)d_in[0];
  const float* adj    = (const float*)d_in[1];
  const float* gcw    = (const float*)d_in[2];
  const float* Wf  = (const float*)d_in[3];  const float* bf_ = (const float*)d_in[4];
  const float* Wi  = (const float*)d_in[5];  const float* bi_ = (const float*)d_in[6];
  const float* Wo  = (const float*)d_in[7];  const float* bo_ = (const float*)d_in[8];
  const float* Wc  = (const float*)d_in[9];  const float* bc_ = (const float*)d_in[10];
  const float* rWf = (const float*)d_in[11]; const float* rbf = (const float*)d_in[12];
  const float* rWi = (const float*)d_in[13]; const float* rbi = (const float*)d_in[14];
  const float* rWo = (const float*)d_in[15]; const float* rbo = (const float*)d_in[16];
  const float* rWc = (const float*)d_in[17]; const float* rbc = (const float*)d_in[18];
  const float* nw     = (const float*)d_in[19];
  const float* cscal  = (const float*)d_in[20];
  const float* convw  = (const float*)d_in[21];
  const float* convb  = (const float*)d_in[22];
  float* out = (float*)d_out;

  char* cur = (char*)d_ws;
  auto alloc = [&](size_t bytes) -> void* {
    void* p = cur; cur += (bytes + 255) & ~(size_t)255; return p;
  };
  u16*   Xb     = (u16*)  alloc((size_t)LS*BC*NN*2);      // 6 MB
  float* csum   = (float*)alloc((size_t)64*1024*4);
  float* tmpv   = (float*)alloc(1024*4);
  u16*   anormT = (u16*)  alloc((size_t)NN*NN*2);         // 2 MB
  u16*   Apowb  = (u16*)  alloc((size_t)3*NN*NN*2);       // 6 MB
  float* nbrv   = (float*)alloc(1024*4);
  u16*   effb   = (u16*)  alloc((size_t)3*NN*NN*2);       // 6 MB
  u16*   effbT  = (u16*)  alloc((size_t)3*NN*NN*2);       // 6 MB
  u16*   Wgxb   = (u16*)  alloc((size_t)4096*3072*2);     // 24 MB
  u16*   WgHp   = (u16*)  alloc((size_t)4096*1024*2);     // 8 MB
  u16*   rWgHp  = (u16*)  alloc((size_t)4096*1024*2);     // 8 MB
  u16*   Bcat   = (u16*)  alloc((size_t)8192*1024*2);     // 16 MB: [Cw; rWgx]
  float* bgcat  = (float*)alloc(8192*4);
  u16*   gclb   = (u16*)  alloc((size_t)BC*3072*2);
  u16*   prebuf = (u16*)  alloc((size_t)3072*8192*2);     // 48 MB bf16
  char*  zbase  = cur;
  u16*   Hb2    = (u16*)  alloc((size_t)2*BC*NN*2);
  u16*   rHb2   = (u16*)  alloc((size_t)2*BC*NN*2);
  float* Cs     = (float*)alloc((size_t)BC*NN*4);
  float* rCs    = (float*)alloc((size_t)BC*NN*4);
  size_t zlen   = (size_t)(cur - zbase);
  float* Hfv    = (float*)alloc((size_t)BC*NN*4);
  float* rHfv   = (float*)alloc((size_t)BC*NN*4);
  float* part   = (float*)alloc(64*4*4);

  u16* A1b = Apowb;
  u16* A2b = Apowb + (size_t)NN*NN;
  u16* A3b = Apowb + (size_t)2*NN*NN;
  u16* Cwb   = Bcat;                       // rows 0..4095
  u16* rWgxb = Bcat + (size_t)4096*1024;   // rows 4096..8191

  // fused preprocessing: transpose + colsum1 + packbias + pack
  k_prep<<<592 + (16777216+8388608)/256, 256, 0, stream>>>(
      inputs, adj, Wf, Wi, Wo, Wc, rWf, rWi, rWo, rWc,
      bf_, bi_, bo_, bc_, rbf, rbi, rbo, rbc,
      Xb, csum, Wgxb, WgHp, rWgxb, rWgHp, bgcat);
  k_colsum2<<<4, 256, 0, stream>>>(csum, tmpv);
  dim3 g16(16, 16);
  k_anormT<<<g16, 256, 0, stream>>>(adj, tmpv, A1b, anormT);
  // adjacency powers, 64^2 tiles BK=128
  k_mfma64<<<g16, 256, 0, stream>>>(A1b, anormT, 1024, 1, A2b, 1024);
  k_mfma64<<<g16, 256, 0, stream>>>(A2b, anormT, 1024, 1, A3b, 1024);
  k_nbr<<<NN, 256, 0, stream>>>(A3b, nw, nbrv);
  dim3 geff(16, 48);
  k_effT<<<geff, 256, 0, stream>>>(Apowb, gcw, effb, effbT);

  // Cw = Wgx @ eff (4096x1024, K=3072), 64^2 tiles BK=128 -> 1024 blocks
  dim3 gcwg(16, 64);
  k_mfma64<<<gcwg, 256, 0, stream>>>(Wgxb, effbT, 3072, 0, Cwb, 1024);
  // pre = X @ [Cw; rWgx]^T + biascat (3072x8192, K=1024), bf16 out
  dim3 gpre(64, 24);
  k_mfma_nt<<<gpre, 256, 0, stream>>>(Xb, Bcat, 1024, bgcat, nullptr, prebuf, 8192);
  // last-step gc (for var only)
  dim3 ggcl(48, 2);
  k_mfma64<<<ggcl, 256, 0, stream>>>(Xb + (size_t)(LS-1)*BC*NN, effb, 1024, 0, gclb, 3072);

  hipMemsetAsync(zbase, 0, zlen, stream);

  // 24 fused steps
  for (int t = 0; t < LS; ++t)
    k_step<<<1024, 256, 0, stream>>>(WgHp, rWgHp,
        prebuf + (size_t)t*BC*8192,
        nbrv, Hb2, rHb2, Cs, rCs, Hfv, rHfv, t & 1, t == LS-1);

  k_var1<<<64, 256, 0, stream>>>(Xb + (size_t)(LS-1)*BC*NN, gclb, part);
  k_out<<<(64*1024)/256, 256, 0, stream>>>(Hfv, rHfv, part, cscal, convw, convb, out);
}